// Round 11
// baseline (341.711 us; speedup 1.0000x reference)
//
#include <hip/hip_runtime.h>

#define NTB 25

typedef float f32x4 __attribute__((ext_vector_type(4)));
typedef short bf16x8 __attribute__((ext_vector_type(8)));

__device__ __forceinline__ ushort f2bf(float f) {
    union { float f; uint u; } v; v.f = f;
    uint u = v.u;
    return (ushort)((u + 0x7fffu + ((u >> 16) & 1u)) >> 16);
}
__device__ __forceinline__ float bf2f(ushort h) {
    union { uint u; float f; } v; v.u = ((uint)h) << 16;
    return v.f;
}
// fragment-block element offset: element (p, k32) of a 16x32 tile stored
// so that lane l owns u16 slots l*8..l*8+7 = (p=l&15, k=(l>>4)*8+j).
__device__ __forceinline__ int foff(int p, int k32) {
    return (((p & 15) | (((k32 >> 3) & 3) << 4)) << 3) + (k32 & 7);
}

// ---------------- K0: weights f32 -> frag-swizzled bf16 ----------------
__global__ __launch_bounds__(256) void k0_wconv(
    const float* __restrict__ gw, const float* __restrict__ tw,
    const float* __restrict__ Ww,
    ushort* __restrict__ gwb, ushort* __restrict__ twb, ushort* __restrict__ Wbf)
{
    int idx = blockIdx.x * 256 + threadIdx.x;
    if (idx < 8192) {
        const float* src = (idx < 4096) ? gw : tw;
        ushort* dst = (idx < 4096) ? gwb : twb;
        int u = idx & 4095;
        int o = u >> 5, c0 = (u & 31) << 3;
        ushort* d = dst + ((o >> 4) * 8 + (c0 >> 5)) * 512 + foff(o, c0 & 31);
        #pragma unroll
        for (int j = 0; j < 8; ++j) d[j] = f2bf(src[o * 256 + c0 + j]);
    } else if (idx < 12288) {
        int u = idx - 8192;
        int o = u >> 4, c0 = (u & 15) << 3;
        ushort* d = Wbf + ((o >> 4) * 4 + (c0 >> 5)) * 512 + foff(o, c0 & 31);
        #pragma unroll
        for (int j = 0; j < 8; ++j) d[j] = f2bf(Ww[o * 128 + c0 + j]);
    }
}

// ---------------- K1a: x f32[b][c][n] -> xT frag-swizzled bf16 (rows n, k c) ----------------
__global__ __launch_bounds__(256) void k1a_xpose(const float* __restrict__ x,
                                                 ushort* __restrict__ xT)
{
    int blk = blockIdx.x;
    int nt = blk % NTB; blk /= NTB;
    int cb = blk & 3; int b = blk >> 2;
    int n0 = nt * 64, c0 = cb * 64;
    __shared__ ushort lds[64 * 70];
    int tid = threadIdx.x;

    const float* xb = x + ((size_t)b * 256 + c0) * 1600 + n0;
    #pragma unroll
    for (int p = 0; p < 4; ++p) {
        int idx = tid + p * 256;
        int c = idx >> 4, n4 = idx & 15;
        f32x4 v = __builtin_nontemporal_load(
            reinterpret_cast<const f32x4*>(&xb[(size_t)c * 1600 + n4 * 4]));
        ushort4 pk;
        pk.x = f2bf(v[0]); pk.y = f2bf(v[1]); pk.z = f2bf(v[2]); pk.w = f2bf(v[3]);
        *reinterpret_cast<ushort4*>(&lds[c * 70 + n4 * 4]) = pk;
    }
    __syncthreads();
    #pragma unroll
    for (int q = 0; q < 2; ++q) {
        int t2 = tid + q * 256;
        int nl = t2 >> 3, c8 = t2 & 7;
        int n = n0 + nl, c = c0 + c8 * 8;
        bf16x8 r;
        #pragma unroll
        for (int j = 0; j < 8; ++j)
            r[j] = (short)lds[(c8 * 8 + j) * 70 + nl];
        *reinterpret_cast<bf16x8*>(
            &xT[(size_t)b * 409600 + (size_t)((n >> 4) * 8 + (c >> 5)) * 512 +
                foff(n, c & 31)]) = r;
    }
}

// ---------------- K1b: barrier-free dual conv1x1, all-frag operands ----------------
__global__ __launch_bounds__(256) void k1b_conv(
    const ushort* __restrict__ xT,
    const ushort* __restrict__ gwb, const float* __restrict__ gb,
    const ushort* __restrict__ twb, const float* __restrict__ tb,
    ushort* __restrict__ gout, ushort* __restrict__ thT)
{
    int nt = blockIdx.x % NTB, b = blockIdx.x / NTB;
    int n0 = nt * 64;
    int tid = threadIdx.x, lane = tid & 63, w = tid >> 6;
    int lr = lane & 15, lg = lane >> 4;
    const ushort* xb = xT + (size_t)b * 409600;

    if (w < 2) {
        int o0 = w * 64;
        f32x4 acc[4][4] = {};
        #pragma unroll
        for (int kc = 0; kc < 8; ++kc) {
            bf16x8 a[4], bf[4];
            #pragma unroll
            for (int mi = 0; mi < 4; ++mi)
                a[mi] = *reinterpret_cast<const bf16x8*>(
                    &xb[(size_t)(((n0 >> 4) + mi) * 8 + kc) * 512 + lane * 8]);
            #pragma unroll
            for (int ni = 0; ni < 4; ++ni)
                bf[ni] = *reinterpret_cast<const bf16x8*>(
                    &gwb[(size_t)(((o0 >> 4) + ni) * 8 + kc) * 512 + lane * 8]);
            #pragma unroll
            for (int mi = 0; mi < 4; ++mi)
                #pragma unroll
                for (int ni = 0; ni < 4; ++ni)
                    acc[mi][ni] = __builtin_amdgcn_mfma_f32_16x16x32_bf16(
                        a[mi], bf[ni], acc[mi][ni], 0, 0, 0);
        }
        #pragma unroll
        for (int ni = 0; ni < 4; ++ni) {
            int o = o0 + ni * 16 + lr;
            float bs = gb[o];
            ushort* gp = &gout[((size_t)b * 128 + o) * 1600 + n0];
            #pragma unroll
            for (int mi = 0; mi < 4; ++mi) {
                ushort4 pk;
                pk.x = f2bf(acc[mi][ni][0] + bs);
                pk.y = f2bf(acc[mi][ni][1] + bs);
                pk.z = f2bf(acc[mi][ni][2] + bs);
                pk.w = f2bf(acc[mi][ni][3] + bs);
                *reinterpret_cast<ushort4*>(&gp[mi * 16 + lg * 4]) = pk;
            }
        }
    } else {
        int o0 = (w - 2) * 64;
        f32x4 acc[4][4] = {};
        #pragma unroll
        for (int kc = 0; kc < 8; ++kc) {
            bf16x8 a[4], bf[4];
            #pragma unroll
            for (int mi = 0; mi < 4; ++mi)
                a[mi] = *reinterpret_cast<const bf16x8*>(
                    &twb[(size_t)(((o0 >> 4) + mi) * 8 + kc) * 512 + lane * 8]);
            #pragma unroll
            for (int ni = 0; ni < 4; ++ni)
                bf[ni] = *reinterpret_cast<const bf16x8*>(
                    &xb[(size_t)(((n0 >> 4) + ni) * 8 + kc) * 512 + lane * 8]);
            #pragma unroll
            for (int mi = 0; mi < 4; ++mi)
                #pragma unroll
                for (int ni = 0; ni < 4; ++ni)
                    acc[mi][ni] = __builtin_amdgcn_mfma_f32_16x16x32_bf16(
                        a[mi], bf[ni], acc[mi][ni], 0, 0, 0);
        }
        #pragma unroll
        for (int mi = 0; mi < 4; ++mi) {
            float4 tbv = *reinterpret_cast<const float4*>(&tb[o0 + mi * 16 + lg * 4]);
            float tbb[4] = {tbv.x, tbv.y, tbv.z, tbv.w};
            int cq = o0 + mi * 16 + lg * 4;
            #pragma unroll
            for (int ni = 0; ni < 4; ++ni) {
                int n = n0 + ni * 16 + lr;
                ushort4 pk;
                pk.x = f2bf(acc[mi][ni][0] + tbb[0]);
                pk.y = f2bf(acc[mi][ni][1] + tbb[1]);
                pk.z = f2bf(acc[mi][ni][2] + tbb[2]);
                pk.w = f2bf(acc[mi][ni][3] + tbb[3]);
                *reinterpret_cast<ushort4*>(
                    &thT[(size_t)b * 204800 + (size_t)((n >> 4) * 4 + (cq >> 5)) * 512 +
                         foff(n, cq & 31)]) = pk;
            }
        }
    }
}

// ---------------- K2: PSP pooling v3 (direct-global row reads, coalesced writes) ----------------
__global__ __launch_bounds__(256) void k2a_psp(const ushort* __restrict__ g,
                                               ushort* __restrict__ phiC,
                                               ushort* __restrict__ phiT)
{
    int cc = blockIdx.x & 7, b = blockIdx.x >> 3;
    __shared__ ushort pooled[16][776];
    int tid = threadIdx.x;

    #pragma unroll
    for (int it = 0; it < 2; ++it) {
        int item = tid + it * 256;
        if (item < 400) {
            int cl = item / 25, r = item % 25;
            const ushort* gp = g + ((size_t)((b * 128 + cc * 16 + cl) * 25 + r)) * 64;
            float S4[16];
            #pragma unroll
            for (int q = 0; q < 8; ++q) {
                bf16x8 v = *reinterpret_cast<const bf16x8*>(&gp[q * 8]);
                S4[q * 2]     = bf2f((ushort)v[0]) + bf2f((ushort)v[1]) +
                                bf2f((ushort)v[2]) + bf2f((ushort)v[3]);
                S4[q * 2 + 1] = bf2f((ushort)v[4]) + bf2f((ushort)v[5]) +
                                bf2f((ushort)v[6]) + bf2f((ushort)v[7]);
            }
            float S8[8], S16[4];
            float tot = 0.f;
            #pragma unroll
            for (int k = 0; k < 8; ++k) S8[k] = S4[2 * k] + S4[2 * k + 1];
            #pragma unroll
            for (int k = 0; k < 4; ++k) { S16[k] = S8[2 * k] + S8[2 * k + 1]; tot += S16[k]; }
            ushort* row = pooled[cl];
            row[r] = f2bf(tot * (1.f / 64.f));
            #pragma unroll
            for (int k = 0; k < 4; ++k)  row[25 + 4 * r + k]  = f2bf(S16[k] * 0.0625f);
            #pragma unroll
            for (int k = 0; k < 8; ++k)  row[125 + 8 * r + k] = f2bf(S8[k] * 0.125f);
            #pragma unroll
            for (int k = 0; k < 16; ++k) row[325 + 16 * r + k] = f2bf(S4[k] * 0.25f);
        }
    }
    if (tid < 16) {
        ushort* row = pooled[tid];
        for (int j = 725; j < 768; ++j) row[j] = 0;
    }
    __syncthreads();

    {
        ushort* pc = phiC + (size_t)(b * 128 + cc * 16) * 768;
        #pragma unroll
        for (int i = 0; i < 6; ++i) {
            int q = tid + i * 256;
            int cl = q / 96, j8 = (q % 96) * 8;
            bf16x8 v = *reinterpret_cast<const bf16x8*>(&pooled[cl][j8]);
            *reinterpret_cast<bf16x8*>(&pc[(size_t)cl * 768 + j8]) = v;
        }
    }
    {
        ushort* pt = phiT + (size_t)b * 98304 + (size_t)(cc >> 1) * 512 + (cc & 1) * 256;
        #pragma unroll
        for (int i = 0; i < 6; ++i) {
            int slot = tid + i * 256;
            int jt = slot >> 5, lh = slot & 31;
            int jl = jt * 16 + (lh & 15);
            int cb8 = (lh >> 4) * 8;
            bf16x8 v;
            #pragma unroll
            for (int jj = 0; jj < 8; ++jj)
                v[jj] = (short)pooled[cb8 + jj][jl];
            *reinterpret_cast<bf16x8*>(&pt[(size_t)(jt * 4) * 512 + lh * 8]) = v;
        }
    }
}

// ---------------- K3: E = exp(theta^T phi) + column-sum partials ----------------
// psum PLANE-MAJOR: psum[nt][b][s].
__global__ __launch_bounds__(256) void k3_expf(
    const ushort* __restrict__ thT, const ushort* __restrict__ phiT,
    ushort* __restrict__ E, float* __restrict__ psum, int b0)
{
    int blk = blockIdx.x;
    int st = blk % 12; blk /= 12;
    int nt = blk % 25; int bl = blk / 25;
    int b = b0 + bl;
    int n0 = nt * 64, s0 = st * 64;
    int tid = threadIdx.x, lane = tid & 63, w = tid >> 6;
    int lr = lane & 15, lg = lane >> 4;

    __shared__ ushort Bs[8192];
    __shared__ float red[64][4];

    {
        const ushort* src = phiT + (size_t)b * 98304 + (size_t)(s0 >> 4) * 2048;
        #pragma unroll
        for (int t = 0; t < 4; ++t) {
            int o8 = (t * 256 + tid) * 8;
            *reinterpret_cast<bf16x8*>(&Bs[o8]) =
                *reinterpret_cast<const bf16x8*>(&src[o8]);
        }
    }
    bf16x8 A[4];
    #pragma unroll
    for (int kc = 0; kc < 4; ++kc)
        A[kc] = *reinterpret_cast<const bf16x8*>(
            &thT[(size_t)b * 204800 + (size_t)(((n0 >> 4) + w) * 4 + kc) * 512 + lane * 8]);
    __syncthreads();

    f32x4 acc[4] = {};
    #pragma unroll
    for (int kc = 0; kc < 4; ++kc)
        #pragma unroll
        for (int ni = 0; ni < 4; ++ni) {
            bf16x8 bb = *reinterpret_cast<const bf16x8*>(&Bs[(ni * 4 + kc) * 512 + lane * 8]);
            acc[ni] = __builtin_amdgcn_mfma_f32_16x16x32_bf16(A[kc], bb, acc[ni], 0, 0, 0);
        }

    size_t ebase = (size_t)bl * 1228800 + (size_t)(((n0 >> 4) + w) * 24 + (s0 >> 5)) * 512;
    #pragma unroll
    for (int ni = 0; ni < 4; ++ni) {
        float se = 0.f;
        float ex[4];
        #pragma unroll
        for (int r = 0; r < 4; ++r) { ex[r] = __expf(acc[ni][r]); se += ex[r]; }
        int scadd = (ni >> 1) * 512;
        int khi = ((ni & 1) * 2 + (lr >> 3)) & 3;
        #pragma unroll
        for (int r = 0; r < 4; ++r) {
            int p = lg * 4 + r;
            E[ebase + scadd + ((p | (khi << 4)) << 3) + (lr & 7)] = f2bf(ex[r]);
        }
        se += __shfl_xor(se, 16);
        se += __shfl_xor(se, 32);
        if (lg == 0) red[ni * 16 + lr][w] = se;
    }
    __syncthreads();
    if (tid < 64) {
        float z = red[tid][0] + red[tid][1] + red[tid][2] + red[tid][3];
        psum[(size_t)nt * 49152 + (size_t)b * 768 + s0 + tid] = z;
    }
}

// ---------------- K4a: zinv[bh][s] = 1/sum over nt planes ----------------
__global__ __launch_bounds__(256) void k4a_zinv(const float* __restrict__ psum,
                                                float* __restrict__ zinv, int b0)
{
    int idx = blockIdx.x * 256 + threadIdx.x;
    if (idx >= 32 * 768) return;
    int s = idx % 768, bh = idx / 768;
    size_t base = (size_t)(b0 + bh) * 768 + s;
    float z = 0.f;
    #pragma unroll
    for (int i = 0; i < 25; ++i) z += psum[(size_t)i * 49152 + base];
    zinv[idx] = (s < 725) ? 1.f / z : 0.f;
}

// ---------------- K4b: phiZ frag-blocks = phiC * zinv, fully coalesced ----------------
__global__ __launch_bounds__(256) void k4b_scale(const ushort* __restrict__ phiC,
                                                 const float* __restrict__ zinv,
                                                 ushort* __restrict__ phiZ)
{
    int idx = blockIdx.x * 256 + threadIdx.x;
    int l = idx & 63;
    int t = idx >> 6;
    int bi = t % 192, b = t / 192;
    int c = (bi / 24) * 16 + (l & 15);
    int s0 = (bi % 24) * 32 + (l >> 4) * 8;
    bf16x8 v = *reinterpret_cast<const bf16x8*>(&phiC[((size_t)b * 128 + c) * 768 + s0]);
    float4 z0 = *reinterpret_cast<const float4*>(&zinv[b * 768 + s0]);
    float4 z1 = *reinterpret_cast<const float4*>(&zinv[b * 768 + s0 + 4]);
    float zz[8] = {z0.x, z0.y, z0.z, z0.w, z1.x, z1.y, z1.z, z1.w};
    bf16x8 r;
    #pragma unroll
    for (int j = 0; j < 8; ++j) r[j] = (short)f2bf(bf2f((ushort)v[j]) * zz[j]);
    *reinterpret_cast<bf16x8*>(&phiZ[(size_t)b * 98304 + (size_t)bi * 512 + l * 8]) = r;
}

// ---------------- K5: y = E @ phiZ^T, 32 rows/wave, depth-3 prefetch ----------------
__global__ __launch_bounds__(64, 2) void k5_pv(
    const ushort* __restrict__ E, const ushort* __restrict__ phiZ,
    ushort* __restrict__ y, float* __restrict__ ypz, int b0)
{
    int ng2 = blockIdx.x % 50, bl = blockIdx.x / 50;
    int b = b0 + bl;
    int lane = threadIdx.x;
    int lr = lane & 15, lg = lane >> 4;
    const ushort* Eb = E + (size_t)bl * 1228800 + (size_t)(ng2 * 2) * 24 * 512 + lane * 8;
    const ushort* Pb = phiZ + (size_t)b * 98304 + lane * 8;

    f32x4 acc[2][8] = {};
    bf16x8 Ab[3][2], Bb[3][8];
    #pragma unroll
    for (int p = 0; p < 3; ++p) {
        Ab[p][0] = *reinterpret_cast<const bf16x8*>(&Eb[(size_t)p * 512]);
        Ab[p][1] = *reinterpret_cast<const bf16x8*>(&Eb[(size_t)(24 + p) * 512]);
        #pragma unroll
        for (int cf = 0; cf < 8; ++cf)
            Bb[p][cf] = *reinterpret_cast<const bf16x8*>(&Pb[(size_t)(cf * 24 + p) * 512]);
    }
    #pragma unroll
    for (int kc = 0; kc < 24; ++kc) {
        int cur = kc % 3;
        bf16x8 a0 = Ab[cur][0], a1 = Ab[cur][1];
        #pragma unroll
        for (int cf = 0; cf < 8; ++cf) {
            bf16x8 bbv = Bb[cur][cf];
            acc[0][cf] = __builtin_amdgcn_mfma_f32_16x16x32_bf16(a0, bbv, acc[0][cf], 0, 0, 0);
            acc[1][cf] = __builtin_amdgcn_mfma_f32_16x16x32_bf16(a1, bbv, acc[1][cf], 0, 0, 0);
        }
        if (kc + 3 < 24) {
            Ab[cur][0] = *reinterpret_cast<const bf16x8*>(&Eb[(size_t)(kc + 3) * 512]);
            Ab[cur][1] = *reinterpret_cast<const bf16x8*>(&Eb[(size_t)(24 + kc + 3) * 512]);
            #pragma unroll
            for (int cf = 0; cf < 8; ++cf)
                Bb[cur][cf] = *reinterpret_cast<const bf16x8*>(
                    &Pb[(size_t)(cf * 24 + kc + 3) * 512]);
        }
    }

    #pragma unroll
    for (int m = 0; m < 2; ++m) {
        int ng = ng2 * 2 + m;
        int nrow = ng * 16;
        #pragma unroll
        for (int cf = 0; cf < 8; ++cf) {
            float se = 0.f;
            #pragma unroll
            for (int r = 0; r < 4; ++r) {
                ushort hv = f2bf(acc[m][cf][r]);
                y[((size_t)b * 1600 + nrow + lg * 4 + r) * 128 + cf * 16 + lr] = hv;
                se += __expf(bf2f(hv));
            }
            se += __shfl_xor(se, 16);
            se += __shfl_xor(se, 32);
            if (lane < 16)
                ypz[((size_t)ng * 64 + b) * 128 + cf * 16 + lane] = se;
        }
    }
}

// ---------------- K6b: combine 100 plane-major partials -> 1/Z2 per (b,c) ----------------
__global__ void k6b_ycomb(const float* __restrict__ ypz, float* __restrict__ yzi)
{
    int idx = blockIdx.x * 256 + threadIdx.x;
    if (idx >= 64 * 128) return;
    float z = 0.f;
    for (int ng = 0; ng < 100; ++ng) z += ypz[(size_t)ng * 8192 + idx];
    yzi[idx] = 1.f / z;
}

// ---------------- K7: softmax(y) -> conv W + residual + BN + ReLU ----------------
// v2: LDS-retransposed epilogue -> float4 nontemporal x loads / out stores.
__global__ __launch_bounds__(256) void k7_final(
    const ushort* __restrict__ y, const float* __restrict__ yzi,
    const ushort* __restrict__ Wbf, const float* __restrict__ Wb,
    const float* __restrict__ x,
    const float* __restrict__ gamma, const float* __restrict__ beta,
    const float* __restrict__ mean, const float* __restrict__ var,
    float* __restrict__ out)
{
    int nt = blockIdx.x % NTB, b = blockIdx.x / NTB;
    int n0 = nt * 64;
    __shared__ __align__(16) char buf[20480];   // yl (17408B) then os (20480B)
    ushort (*yl)[136] = reinterpret_cast<ushort(*)[136]>(buf);
    float (*os)[20]   = reinterpret_cast<float(*)[20]>(buf);
    __shared__ float scl[256], shl[256], wbl[256], zl[128];
    int t = threadIdx.x, lane = t & 63, w = t >> 6;
    {
        float sc = gamma[t] * rsqrtf(var[t] + 1e-5f);
        scl[t] = sc;
        shl[t] = beta[t] - mean[t] * sc;
        wbl[t] = Wb[t];
        if (t < 128) zl[t] = yzi[(size_t)b * 128 + t];
    }
    __syncthreads();
    int c8 = (t & 15) * 8, rr = t >> 4;
    #pragma unroll
    for (int p = 0; p < 4; ++p) {
        int r = rr + 16 * p;
        bf16x8 v = *reinterpret_cast<const bf16x8*>(
            &y[((size_t)b * 1600 + n0 + r) * 128 + c8]);
        bf16x8 pk;
        #pragma unroll
        for (int j = 0; j < 8; ++j) {
            float f = bf2f((ushort)v[j]);
            pk[j] = (short)f2bf(__expf(f) * zl[c8 + j]);
        }
        *reinterpret_cast<bf16x8*>(&yl[r][c8]) = pk;
    }
    __syncthreads();
    int lr = lane & 15, lg = lane >> 4;
    int o0 = w * 64;
    f32x4 acc[4][4] = {};
    #pragma unroll
    for (int kc = 0; kc < 4; ++kc) {
        bf16x8 af[4];
        #pragma unroll
        for (int mi = 0; mi < 4; ++mi)
            af[mi] = *reinterpret_cast<const bf16x8*>(
                &Wbf[(size_t)(((o0 >> 4) + mi) * 4 + kc) * 512 + lane * 8]);
        #pragma unroll
        for (int ni = 0; ni < 4; ++ni) {
            bf16x8 bfrag = *reinterpret_cast<const bf16x8*>(&yl[ni * 16 + lr][kc * 32 + lg * 8]);
            #pragma unroll
            for (int mi = 0; mi < 4; ++mi)
                acc[mi][ni] = __builtin_amdgcn_mfma_f32_16x16x32_bf16(
                    af[mi], bfrag, acc[mi][ni], 0, 0, 0);
        }
    }
    // epilogue: retranspose each 256o x 16n slab via LDS -> vectorized stream
    #pragma unroll
    for (int pass = 0; pass < 4; ++pass) {
        __syncthreads();    // yl reads (pass 0) / prev-pass os reads done
        #pragma unroll
        for (int mi = 0; mi < 4; ++mi)
            #pragma unroll
            for (int r = 0; r < 4; ++r)
                os[o0 + mi * 16 + lg * 4 + r][lr] = acc[mi][pass][r];
        __syncthreads();
        #pragma unroll
        for (int it = 0; it < 4; ++it) {
            int idx = it * 256 + t;          // 0..1023
            int o = idx >> 2, nq = idx & 3;
            int n = n0 + pass * 16 + nq * 4;
            f32x4 vr = *reinterpret_cast<f32x4*>(&os[o][nq * 4]);
            size_t off = ((size_t)b * 256 + o) * 1600 + n;
            f32x4 xr = __builtin_nontemporal_load(
                reinterpret_cast<const f32x4*>(&x[off]));
            float sc = scl[o], sh = shl[o], wb = wbl[o];
            f32x4 r4;
            #pragma unroll
            for (int j = 0; j < 4; ++j)
                r4[j] = fmaxf((vr[j] + wb + xr[j]) * sc + sh, 0.f);
            __builtin_nontemporal_store(r4, reinterpret_cast<f32x4*>(&out[off]));
        }
    }
}

extern "C" void kernel_launch(void* const* d_in, const int* in_sizes, int n_in,
                              void* d_out, int out_size, void* d_ws, size_t ws_size,
                              hipStream_t stream)
{
    const float* x   = (const float*)d_in[0];
    const float* gw  = (const float*)d_in[1];
    const float* gb  = (const float*)d_in[2];
    const float* tw  = (const float*)d_in[3];
    const float* tb  = (const float*)d_in[4];
    const float* Ww  = (const float*)d_in[5];
    const float* Wb  = (const float*)d_in[6];
    const float* bng = (const float*)d_in[7];
    const float* bnb = (const float*)d_in[8];
    const float* bnm = (const float*)d_in[9];
    const float* bnv = (const float*)d_in[10];
    float* out = (float*)d_out;

    char* base = (char*)d_ws;
    ushort* thT  = (ushort*)(base);               // 26,214,400 B (frag-swz)
    ushort* gout = (ushort*)(base + 26214400);    // 26,214,400 B (reused as y)
    ushort* phiC = (ushort*)(base + 52428800);    // 12,582,912 B (row-major)
    ushort* phiT = (ushort*)(base + 65011712);    // 12,582,912 B (frag-swz)
    float* psum  = (float*)(base + 77594624);     //  4,915,200 B  [nt][b][s]
    ushort* phiZ = (ushort*)(base + 82509824);    // 12,582,912 B (frag-swz)
    float* zinv  = (float*)(base + 95092736);     //    196,608 B
    float* ypz   = (float*)(base + 95289344);     //  3,276,800 B  [ng][b][c]
    float* yzi   = (float*)(base + 98566144);     //     32,768 B
    ushort* Wbf  = (ushort*)(base + 98598912);    //     65,536 B (frag-swz)
    ushort* gwb  = (ushort*)(base + 98664448);    //     65,536 B (frag-swz)
    ushort* twb  = (ushort*)(base + 98729984);    //     65,536 B (frag-swz)
    ushort* yv   = gout;                          // alias: gout dead after k2a
    ushort* xT   = (ushort*)d_out;                // scratch in out region
    ushort* E    = (ushort*)d_out;

    k0_wconv<<<48, 256, 0, stream>>>(gw, tw, Ww, gwb, twb, Wbf);
    k1a_xpose<<<64 * 4 * NTB, 256, 0, stream>>>(x, xT);
    k1b_conv<<<64 * NTB, 256, 0, stream>>>(xT, gwb, gb, twb, tb, gout, thT);
    k2a_psp<<<64 * 8, 256, 0, stream>>>(gout, phiC, phiT);

    // half 0: batches 0..31
    k3_expf<<<32 * 25 * 12, 256, 0, stream>>>(thT, phiT, E, psum, 0);
    k4a_zinv<<<96, 256, 0, stream>>>(psum, zinv, 0);
    k4b_scale<<<1536, 256, 0, stream>>>(phiC, zinv, phiZ);
    k5_pv<<<32 * 50, 64, 0, stream>>>(E, phiZ, yv, ypz, 0);

    // half 1: batches 32..63
    k3_expf<<<32 * 25 * 12, 256, 0, stream>>>(thT, phiT, E, psum, 32);
    k4a_zinv<<<96, 256, 0, stream>>>(psum, zinv, 32);
    k4b_scale<<<1536, 256, 0, stream>>>(phiC + (size_t)32 * 128 * 768, zinv,
                                        phiZ + (size_t)32 * 98304);
    k5_pv<<<32 * 50, 64, 0, stream>>>(E, phiZ, yv, ypz, 32);

    k6b_ycomb<<<32, 256, 0, stream>>>(ypz, yzi);
    k7_final<<<64 * NTB, 256, 0, stream>>>(yv, yzi, Wbf, Wb, x, bng, bnb, bnm, bnv, out);
}

// Round 12
// 332.218 us; speedup vs baseline: 1.0286x; 1.0286x over previous
//
#include <hip/hip_runtime.h>

#define NTB 25

typedef float f32x4 __attribute__((ext_vector_type(4)));
typedef short bf16x8 __attribute__((ext_vector_type(8)));

__device__ __forceinline__ ushort f2bf(float f) {
    union { float f; uint u; } v; v.f = f;
    uint u = v.u;
    return (ushort)((u + 0x7fffu + ((u >> 16) & 1u)) >> 16);
}
__device__ __forceinline__ float bf2f(ushort h) {
    union { uint u; float f; } v; v.u = ((uint)h) << 16;
    return v.f;
}
// fragment-block element offset: element (p, k32) of a 16x32 tile stored
// so that lane l owns u16 slots l*8..l*8+7 = (p=l&15, k=(l>>4)*8+j).
__device__ __forceinline__ int foff(int p, int k32) {
    return (((p & 15) | (((k32 >> 3) & 3) << 4)) << 3) + (k32 & 7);
}

// ---------------- K0: weights f32 -> frag-swizzled bf16 ----------------
__global__ __launch_bounds__(256) void k0_wconv(
    const float* __restrict__ gw, const float* __restrict__ tw,
    const float* __restrict__ Ww,
    ushort* __restrict__ gwb, ushort* __restrict__ twb, ushort* __restrict__ Wbf)
{
    int idx = blockIdx.x * 256 + threadIdx.x;
    if (idx < 8192) {
        const float* src = (idx < 4096) ? gw : tw;
        ushort* dst = (idx < 4096) ? gwb : twb;
        int u = idx & 4095;
        int o = u >> 5, c0 = (u & 31) << 3;
        ushort* d = dst + ((o >> 4) * 8 + (c0 >> 5)) * 512 + foff(o, c0 & 31);
        #pragma unroll
        for (int j = 0; j < 8; ++j) d[j] = f2bf(src[o * 256 + c0 + j]);
    } else if (idx < 12288) {
        int u = idx - 8192;
        int o = u >> 4, c0 = (u & 15) << 3;
        ushort* d = Wbf + ((o >> 4) * 4 + (c0 >> 5)) * 512 + foff(o, c0 & 31);
        #pragma unroll
        for (int j = 0; j < 8; ++j) d[j] = f2bf(Ww[o * 128 + c0 + j]);
    }
}

// ---------------- K1a: x f32[b][c][n] -> xT frag-swizzled bf16 (rows n, k c) ----------------
__global__ __launch_bounds__(256) void k1a_xpose(const float* __restrict__ x,
                                                 ushort* __restrict__ xT)
{
    int blk = blockIdx.x;
    int nt = blk % NTB; blk /= NTB;
    int cb = blk & 3; int b = blk >> 2;
    int n0 = nt * 64, c0 = cb * 64;
    __shared__ ushort lds[64 * 70];
    int tid = threadIdx.x;

    const float* xb = x + ((size_t)b * 256 + c0) * 1600 + n0;
    #pragma unroll
    for (int p = 0; p < 4; ++p) {
        int idx = tid + p * 256;
        int c = idx >> 4, n4 = idx & 15;
        float4 v = *reinterpret_cast<const float4*>(&xb[(size_t)c * 1600 + n4 * 4]);
        ushort4 pk;
        pk.x = f2bf(v.x); pk.y = f2bf(v.y); pk.z = f2bf(v.z); pk.w = f2bf(v.w);
        *reinterpret_cast<ushort4*>(&lds[c * 70 + n4 * 4]) = pk;
    }
    __syncthreads();
    #pragma unroll
    for (int q = 0; q < 2; ++q) {
        int t2 = tid + q * 256;
        int nl = t2 >> 3, c8 = t2 & 7;
        int n = n0 + nl, c = c0 + c8 * 8;
        bf16x8 r;
        #pragma unroll
        for (int j = 0; j < 8; ++j)
            r[j] = (short)lds[(c8 * 8 + j) * 70 + nl];
        *reinterpret_cast<bf16x8*>(
            &xT[(size_t)b * 409600 + (size_t)((n >> 4) * 8 + (c >> 5)) * 512 +
                foff(n, c & 31)]) = r;
    }
}

// ---------------- K1b: barrier-free dual conv1x1, all-frag operands ----------------
__global__ __launch_bounds__(256) void k1b_conv(
    const ushort* __restrict__ xT,
    const ushort* __restrict__ gwb, const float* __restrict__ gb,
    const ushort* __restrict__ twb, const float* __restrict__ tb,
    ushort* __restrict__ gout, ushort* __restrict__ thT)
{
    int nt = blockIdx.x % NTB, b = blockIdx.x / NTB;
    int n0 = nt * 64;
    int tid = threadIdx.x, lane = tid & 63, w = tid >> 6;
    int lr = lane & 15, lg = lane >> 4;
    const ushort* xb = xT + (size_t)b * 409600;

    if (w < 2) {
        int o0 = w * 64;
        f32x4 acc[4][4] = {};
        #pragma unroll
        for (int kc = 0; kc < 8; ++kc) {
            bf16x8 a[4], bf[4];
            #pragma unroll
            for (int mi = 0; mi < 4; ++mi)
                a[mi] = *reinterpret_cast<const bf16x8*>(
                    &xb[(size_t)(((n0 >> 4) + mi) * 8 + kc) * 512 + lane * 8]);
            #pragma unroll
            for (int ni = 0; ni < 4; ++ni)
                bf[ni] = *reinterpret_cast<const bf16x8*>(
                    &gwb[(size_t)(((o0 >> 4) + ni) * 8 + kc) * 512 + lane * 8]);
            #pragma unroll
            for (int mi = 0; mi < 4; ++mi)
                #pragma unroll
                for (int ni = 0; ni < 4; ++ni)
                    acc[mi][ni] = __builtin_amdgcn_mfma_f32_16x16x32_bf16(
                        a[mi], bf[ni], acc[mi][ni], 0, 0, 0);
        }
        #pragma unroll
        for (int ni = 0; ni < 4; ++ni) {
            int o = o0 + ni * 16 + lr;
            float bs = gb[o];
            ushort* gp = &gout[((size_t)b * 128 + o) * 1600 + n0];
            #pragma unroll
            for (int mi = 0; mi < 4; ++mi) {
                ushort4 pk;
                pk.x = f2bf(acc[mi][ni][0] + bs);
                pk.y = f2bf(acc[mi][ni][1] + bs);
                pk.z = f2bf(acc[mi][ni][2] + bs);
                pk.w = f2bf(acc[mi][ni][3] + bs);
                *reinterpret_cast<ushort4*>(&gp[mi * 16 + lg * 4]) = pk;
            }
        }
    } else {
        int o0 = (w - 2) * 64;
        f32x4 acc[4][4] = {};
        #pragma unroll
        for (int kc = 0; kc < 8; ++kc) {
            bf16x8 a[4], bf[4];
            #pragma unroll
            for (int mi = 0; mi < 4; ++mi)
                a[mi] = *reinterpret_cast<const bf16x8*>(
                    &twb[(size_t)(((o0 >> 4) + mi) * 8 + kc) * 512 + lane * 8]);
            #pragma unroll
            for (int ni = 0; ni < 4; ++ni)
                bf[ni] = *reinterpret_cast<const bf16x8*>(
                    &xb[(size_t)(((n0 >> 4) + ni) * 8 + kc) * 512 + lane * 8]);
            #pragma unroll
            for (int mi = 0; mi < 4; ++mi)
                #pragma unroll
                for (int ni = 0; ni < 4; ++ni)
                    acc[mi][ni] = __builtin_amdgcn_mfma_f32_16x16x32_bf16(
                        a[mi], bf[ni], acc[mi][ni], 0, 0, 0);
        }
        #pragma unroll
        for (int mi = 0; mi < 4; ++mi) {
            float4 tbv = *reinterpret_cast<const float4*>(&tb[o0 + mi * 16 + lg * 4]);
            float tbb[4] = {tbv.x, tbv.y, tbv.z, tbv.w};
            int cq = o0 + mi * 16 + lg * 4;
            #pragma unroll
            for (int ni = 0; ni < 4; ++ni) {
                int n = n0 + ni * 16 + lr;
                ushort4 pk;
                pk.x = f2bf(acc[mi][ni][0] + tbb[0]);
                pk.y = f2bf(acc[mi][ni][1] + tbb[1]);
                pk.z = f2bf(acc[mi][ni][2] + tbb[2]);
                pk.w = f2bf(acc[mi][ni][3] + tbb[3]);
                *reinterpret_cast<ushort4*>(
                    &thT[(size_t)b * 204800 + (size_t)((n >> 4) * 4 + (cq >> 5)) * 512 +
                         foff(n, cq & 31)]) = pk;
            }
        }
    }
}

// ---------------- K2: PSP pooling v3 (direct-global row reads, coalesced writes) ----------------
__global__ __launch_bounds__(256) void k2a_psp(const ushort* __restrict__ g,
                                               ushort* __restrict__ phiC,
                                               ushort* __restrict__ phiT)
{
    int cc = blockIdx.x & 7, b = blockIdx.x >> 3;
    __shared__ ushort pooled[16][776];
    int tid = threadIdx.x;

    #pragma unroll
    for (int it = 0; it < 2; ++it) {
        int item = tid + it * 256;
        if (item < 400) {
            int cl = item / 25, r = item % 25;
            const ushort* gp = g + ((size_t)((b * 128 + cc * 16 + cl) * 25 + r)) * 64;
            float S4[16];
            #pragma unroll
            for (int q = 0; q < 8; ++q) {
                bf16x8 v = *reinterpret_cast<const bf16x8*>(&gp[q * 8]);
                S4[q * 2]     = bf2f((ushort)v[0]) + bf2f((ushort)v[1]) +
                                bf2f((ushort)v[2]) + bf2f((ushort)v[3]);
                S4[q * 2 + 1] = bf2f((ushort)v[4]) + bf2f((ushort)v[5]) +
                                bf2f((ushort)v[6]) + bf2f((ushort)v[7]);
            }
            float S8[8], S16[4];
            float tot = 0.f;
            #pragma unroll
            for (int k = 0; k < 8; ++k) S8[k] = S4[2 * k] + S4[2 * k + 1];
            #pragma unroll
            for (int k = 0; k < 4; ++k) { S16[k] = S8[2 * k] + S8[2 * k + 1]; tot += S16[k]; }
            ushort* row = pooled[cl];
            row[r] = f2bf(tot * (1.f / 64.f));
            #pragma unroll
            for (int k = 0; k < 4; ++k)  row[25 + 4 * r + k]  = f2bf(S16[k] * 0.0625f);
            #pragma unroll
            for (int k = 0; k < 8; ++k)  row[125 + 8 * r + k] = f2bf(S8[k] * 0.125f);
            #pragma unroll
            for (int k = 0; k < 16; ++k) row[325 + 16 * r + k] = f2bf(S4[k] * 0.25f);
        }
    }
    if (tid < 16) {
        ushort* row = pooled[tid];
        for (int j = 725; j < 768; ++j) row[j] = 0;
    }
    __syncthreads();

    {
        ushort* pc = phiC + (size_t)(b * 128 + cc * 16) * 768;
        #pragma unroll
        for (int i = 0; i < 6; ++i) {
            int q = tid + i * 256;
            int cl = q / 96, j8 = (q % 96) * 8;
            bf16x8 v = *reinterpret_cast<const bf16x8*>(&pooled[cl][j8]);
            *reinterpret_cast<bf16x8*>(&pc[(size_t)cl * 768 + j8]) = v;
        }
    }
    {
        ushort* pt = phiT + (size_t)b * 98304 + (size_t)(cc >> 1) * 512 + (cc & 1) * 256;
        #pragma unroll
        for (int i = 0; i < 6; ++i) {
            int slot = tid + i * 256;
            int jt = slot >> 5, lh = slot & 31;
            int jl = jt * 16 + (lh & 15);
            int cb8 = (lh >> 4) * 8;
            bf16x8 v;
            #pragma unroll
            for (int jj = 0; jj < 8; ++jj)
                v[jj] = (short)pooled[cb8 + jj][jl];
            *reinterpret_cast<bf16x8*>(&pt[(size_t)(jt * 4) * 512 + lh * 8]) = v;
        }
    }
}

// ---------------- K3: E = exp(theta^T phi) + column-sum partials ----------------
// psum PLANE-MAJOR: psum[nt][b][s].
__global__ __launch_bounds__(256) void k3_expf(
    const ushort* __restrict__ thT, const ushort* __restrict__ phiT,
    ushort* __restrict__ E, float* __restrict__ psum, int b0)
{
    int blk = blockIdx.x;
    int st = blk % 12; blk /= 12;
    int nt = blk % 25; int bl = blk / 25;
    int b = b0 + bl;
    int n0 = nt * 64, s0 = st * 64;
    int tid = threadIdx.x, lane = tid & 63, w = tid >> 6;
    int lr = lane & 15, lg = lane >> 4;

    __shared__ ushort Bs[8192];
    __shared__ float red[64][4];

    {
        const ushort* src = phiT + (size_t)b * 98304 + (size_t)(s0 >> 4) * 2048;
        #pragma unroll
        for (int t = 0; t < 4; ++t) {
            int o8 = (t * 256 + tid) * 8;
            *reinterpret_cast<bf16x8*>(&Bs[o8]) =
                *reinterpret_cast<const bf16x8*>(&src[o8]);
        }
    }
    bf16x8 A[4];
    #pragma unroll
    for (int kc = 0; kc < 4; ++kc)
        A[kc] = *reinterpret_cast<const bf16x8*>(
            &thT[(size_t)b * 204800 + (size_t)(((n0 >> 4) + w) * 4 + kc) * 512 + lane * 8]);
    __syncthreads();

    f32x4 acc[4] = {};
    #pragma unroll
    for (int kc = 0; kc < 4; ++kc)
        #pragma unroll
        for (int ni = 0; ni < 4; ++ni) {
            bf16x8 bb = *reinterpret_cast<const bf16x8*>(&Bs[(ni * 4 + kc) * 512 + lane * 8]);
            acc[ni] = __builtin_amdgcn_mfma_f32_16x16x32_bf16(A[kc], bb, acc[ni], 0, 0, 0);
        }

    size_t ebase = (size_t)bl * 1228800 + (size_t)(((n0 >> 4) + w) * 24 + (s0 >> 5)) * 512;
    #pragma unroll
    for (int ni = 0; ni < 4; ++ni) {
        float se = 0.f;
        float ex[4];
        #pragma unroll
        for (int r = 0; r < 4; ++r) { ex[r] = __expf(acc[ni][r]); se += ex[r]; }
        int scadd = (ni >> 1) * 512;
        int khi = ((ni & 1) * 2 + (lr >> 3)) & 3;
        #pragma unroll
        for (int r = 0; r < 4; ++r) {
            int p = lg * 4 + r;
            E[ebase + scadd + ((p | (khi << 4)) << 3) + (lr & 7)] = f2bf(ex[r]);
        }
        se += __shfl_xor(se, 16);
        se += __shfl_xor(se, 32);
        if (lg == 0) red[ni * 16 + lr][w] = se;
    }
    __syncthreads();
    if (tid < 64) {
        float z = red[tid][0] + red[tid][1] + red[tid][2] + red[tid][3];
        psum[(size_t)nt * 49152 + (size_t)b * 768 + s0 + tid] = z;
    }
}

// ---------------- K4a: zinv[bh][s] = 1/sum over nt planes ----------------
__global__ __launch_bounds__(256) void k4a_zinv(const float* __restrict__ psum,
                                                float* __restrict__ zinv, int b0)
{
    int idx = blockIdx.x * 256 + threadIdx.x;
    if (idx >= 32 * 768) return;
    int s = idx % 768, bh = idx / 768;
    size_t base = (size_t)(b0 + bh) * 768 + s;
    float z = 0.f;
    #pragma unroll
    for (int i = 0; i < 25; ++i) z += psum[(size_t)i * 49152 + base];
    zinv[idx] = (s < 725) ? 1.f / z : 0.f;
}

// ---------------- K4b: phiZ frag-blocks = phiC * zinv, fully coalesced ----------------
__global__ __launch_bounds__(256) void k4b_scale(const ushort* __restrict__ phiC,
                                                 const float* __restrict__ zinv,
                                                 ushort* __restrict__ phiZ)
{
    int idx = blockIdx.x * 256 + threadIdx.x;
    int l = idx & 63;
    int t = idx >> 6;
    int bi = t % 192, b = t / 192;
    int c = (bi / 24) * 16 + (l & 15);
    int s0 = (bi % 24) * 32 + (l >> 4) * 8;
    bf16x8 v = *reinterpret_cast<const bf16x8*>(&phiC[((size_t)b * 128 + c) * 768 + s0]);
    float4 z0 = *reinterpret_cast<const float4*>(&zinv[b * 768 + s0]);
    float4 z1 = *reinterpret_cast<const float4*>(&zinv[b * 768 + s0 + 4]);
    float zz[8] = {z0.x, z0.y, z0.z, z0.w, z1.x, z1.y, z1.z, z1.w};
    bf16x8 r;
    #pragma unroll
    for (int j = 0; j < 8; ++j) r[j] = (short)f2bf(bf2f((ushort)v[j]) * zz[j]);
    *reinterpret_cast<bf16x8*>(&phiZ[(size_t)b * 98304 + (size_t)bi * 512 + l * 8]) = r;
}

// ---------------- K5: y = E @ phiZ^T, 32 rows/wave, depth-3 prefetch ----------------
__global__ __launch_bounds__(64, 2) void k5_pv(
    const ushort* __restrict__ E, const ushort* __restrict__ phiZ,
    ushort* __restrict__ y, float* __restrict__ ypz, int b0)
{
    int ng2 = blockIdx.x % 50, bl = blockIdx.x / 50;
    int b = b0 + bl;
    int lane = threadIdx.x;
    int lr = lane & 15, lg = lane >> 4;
    const ushort* Eb = E + (size_t)bl * 1228800 + (size_t)(ng2 * 2) * 24 * 512 + lane * 8;
    const ushort* Pb = phiZ + (size_t)b * 98304 + lane * 8;

    f32x4 acc[2][8] = {};
    bf16x8 Ab[3][2], Bb[3][8];
    #pragma unroll
    for (int p = 0; p < 3; ++p) {
        Ab[p][0] = *reinterpret_cast<const bf16x8*>(&Eb[(size_t)p * 512]);
        Ab[p][1] = *reinterpret_cast<const bf16x8*>(&Eb[(size_t)(24 + p) * 512]);
        #pragma unroll
        for (int cf = 0; cf < 8; ++cf)
            Bb[p][cf] = *reinterpret_cast<const bf16x8*>(&Pb[(size_t)(cf * 24 + p) * 512]);
    }
    #pragma unroll
    for (int kc = 0; kc < 24; ++kc) {
        int cur = kc % 3;
        bf16x8 a0 = Ab[cur][0], a1 = Ab[cur][1];
        #pragma unroll
        for (int cf = 0; cf < 8; ++cf) {
            bf16x8 bbv = Bb[cur][cf];
            acc[0][cf] = __builtin_amdgcn_mfma_f32_16x16x32_bf16(a0, bbv, acc[0][cf], 0, 0, 0);
            acc[1][cf] = __builtin_amdgcn_mfma_f32_16x16x32_bf16(a1, bbv, acc[1][cf], 0, 0, 0);
        }
        if (kc + 3 < 24) {
            Ab[cur][0] = *reinterpret_cast<const bf16x8*>(&Eb[(size_t)(kc + 3) * 512]);
            Ab[cur][1] = *reinterpret_cast<const bf16x8*>(&Eb[(size_t)(24 + kc + 3) * 512]);
            #pragma unroll
            for (int cf = 0; cf < 8; ++cf)
                Bb[cur][cf] = *reinterpret_cast<const bf16x8*>(
                    &Pb[(size_t)(cf * 24 + kc + 3) * 512]);
        }
    }

    #pragma unroll
    for (int m = 0; m < 2; ++m) {
        int ng = ng2 * 2 + m;
        int nrow = ng * 16;
        #pragma unroll
        for (int cf = 0; cf < 8; ++cf) {
            float se = 0.f;
            #pragma unroll
            for (int r = 0; r < 4; ++r) {
                ushort hv = f2bf(acc[m][cf][r]);
                y[((size_t)b * 1600 + nrow + lg * 4 + r) * 128 + cf * 16 + lr] = hv;
                se += __expf(bf2f(hv));
            }
            se += __shfl_xor(se, 16);
            se += __shfl_xor(se, 32);
            if (lane < 16)
                ypz[((size_t)ng * 64 + b) * 128 + cf * 16 + lane] = se;
        }
    }
}

// ---------------- K6b: combine 100 plane-major partials -> 1/Z2 per (b,c) ----------------
__global__ void k6b_ycomb(const float* __restrict__ ypz, float* __restrict__ yzi)
{
    int idx = blockIdx.x * 256 + threadIdx.x;
    if (idx >= 64 * 128) return;
    float z = 0.f;
    for (int ng = 0; ng < 100; ++ng) z += ypz[(size_t)ng * 8192 + idx];
    yzi[idx] = 1.f / z;
}

// ---------------- K7: softmax(y) -> conv W + residual + BN + ReLU ----------------
// v3: round-10 structure, n-tile halved to 32 (grid 3200) for latency hiding.
__global__ __launch_bounds__(256) void k7_final(
    const ushort* __restrict__ y, const float* __restrict__ yzi,
    const ushort* __restrict__ Wbf, const float* __restrict__ Wb,
    const float* __restrict__ x,
    const float* __restrict__ gamma, const float* __restrict__ beta,
    const float* __restrict__ mean, const float* __restrict__ var,
    float* __restrict__ out)
{
    int nt = blockIdx.x % 50, b = blockIdx.x / 50;
    int n0 = nt * 32;
    __shared__ ushort yl[32][136];
    __shared__ float scl[256], shl[256], wbl[256], zl[128];
    int t = threadIdx.x, lane = t & 63, w = t >> 6;
    {
        float sc = gamma[t] * rsqrtf(var[t] + 1e-5f);
        scl[t] = sc;
        shl[t] = beta[t] - mean[t] * sc;
        wbl[t] = Wb[t];
        if (t < 128) zl[t] = yzi[(size_t)b * 128 + t];
    }
    __syncthreads();
    int c8 = (t & 15) * 8, rr = t >> 4;
    #pragma unroll
    for (int p = 0; p < 2; ++p) {
        int r = rr + 16 * p;
        bf16x8 v = *reinterpret_cast<const bf16x8*>(
            &y[((size_t)b * 1600 + n0 + r) * 128 + c8]);
        bf16x8 pk;
        #pragma unroll
        for (int j = 0; j < 8; ++j) {
            float f = bf2f((ushort)v[j]);
            pk[j] = (short)f2bf(__expf(f) * zl[c8 + j]);
        }
        *reinterpret_cast<bf16x8*>(&yl[r][c8]) = pk;
    }
    __syncthreads();
    int lr = lane & 15, lg = lane >> 4;
    int o0 = w * 64;
    f32x4 acc[4][2] = {};
    #pragma unroll
    for (int kc = 0; kc < 4; ++kc) {
        bf16x8 af[4];
        #pragma unroll
        for (int mi = 0; mi < 4; ++mi)
            af[mi] = *reinterpret_cast<const bf16x8*>(
                &Wbf[(size_t)(((o0 >> 4) + mi) * 4 + kc) * 512 + lane * 8]);
        #pragma unroll
        for (int ni = 0; ni < 2; ++ni) {
            bf16x8 bfrag = *reinterpret_cast<const bf16x8*>(&yl[ni * 16 + lr][kc * 32 + lg * 8]);
            #pragma unroll
            for (int mi = 0; mi < 4; ++mi)
                acc[mi][ni] = __builtin_amdgcn_mfma_f32_16x16x32_bf16(
                    af[mi], bfrag, acc[mi][ni], 0, 0, 0);
        }
    }
    #pragma unroll
    for (int mi = 0; mi < 4; ++mi)
        #pragma unroll
        for (int ni = 0; ni < 2; ++ni) {
            int n = n0 + ni * 16 + lr;
            #pragma unroll
            for (int r = 0; r < 4; ++r) {
                int o = o0 + mi * 16 + lg * 4 + r;
                size_t off = ((size_t)b * 256 + o) * 1600 + n;
                float v = (acc[mi][ni][r] + wbl[o] + x[off]) * scl[o] + shl[o];
                out[off] = fmaxf(v, 0.f);
            }
        }
}

extern "C" void kernel_launch(void* const* d_in, const int* in_sizes, int n_in,
                              void* d_out, int out_size, void* d_ws, size_t ws_size,
                              hipStream_t stream)
{
    const float* x   = (const float*)d_in[0];
    const float* gw  = (const float*)d_in[1];
    const float* gb  = (const float*)d_in[2];
    const float* tw  = (const float*)d_in[3];
    const float* tb  = (const float*)d_in[4];
    const float* Ww  = (const float*)d_in[5];
    const float* Wb  = (const float*)d_in[6];
    const float* bng = (const float*)d_in[7];
    const float* bnb = (const float*)d_in[8];
    const float* bnm = (const float*)d_in[9];
    const float* bnv = (const float*)d_in[10];
    float* out = (float*)d_out;

    char* base = (char*)d_ws;
    ushort* thT  = (ushort*)(base);               // 26,214,400 B (frag-swz)
    ushort* gout = (ushort*)(base + 26214400);    // 26,214,400 B (reused as y)
    ushort* phiC = (ushort*)(base + 52428800);    // 12,582,912 B (row-major)
    ushort* phiT = (ushort*)(base + 65011712);    // 12,582,912 B (frag-swz)
    float* psum  = (float*)(base + 77594624);     //  4,915,200 B  [nt][b][s]
    ushort* phiZ = (ushort*)(base + 82509824);    // 12,582,912 B (frag-swz)
    float* zinv  = (float*)(base + 95092736);     //    196,608 B
    float* ypz   = (float*)(base + 95289344);     //  3,276,800 B  [ng][b][c]
    float* yzi   = (float*)(base + 98566144);     //     32,768 B
    ushort* Wbf  = (ushort*)(base + 98598912);    //     65,536 B (frag-swz)
    ushort* gwb  = (ushort*)(base + 98664448);    //     65,536 B (frag-swz)
    ushort* twb  = (ushort*)(base + 98729984);    //     65,536 B (frag-swz)
    ushort* yv   = gout;                          // alias: gout dead after k2a
    ushort* xT   = (ushort*)d_out;                // scratch in out region
    ushort* E    = (ushort*)d_out;

    k0_wconv<<<48, 256, 0, stream>>>(gw, tw, Ww, gwb, twb, Wbf);
    k1a_xpose<<<64 * 4 * NTB, 256, 0, stream>>>(x, xT);
    k1b_conv<<<64 * NTB, 256, 0, stream>>>(xT, gwb, gb, twb, tb, gout, thT);
    k2a_psp<<<64 * 8, 256, 0, stream>>>(gout, phiC, phiT);

    // half 0: batches 0..31
    k3_expf<<<32 * 25 * 12, 256, 0, stream>>>(thT, phiT, E, psum, 0);
    k4a_zinv<<<96, 256, 0, stream>>>(psum, zinv, 0);
    k4b_scale<<<1536, 256, 0, stream>>>(phiC, zinv, phiZ);
    k5_pv<<<32 * 50, 64, 0, stream>>>(E, phiZ, yv, ypz, 0);

    // half 1: batches 32..63
    k3_expf<<<32 * 25 * 12, 256, 0, stream>>>(thT, phiT, E, psum, 32);
    k4a_zinv<<<96, 256, 0, stream>>>(psum, zinv, 32);
    k4b_scale<<<1536, 256, 0, stream>>>(phiC + (size_t)32 * 128 * 768, zinv,
                                        phiZ + (size_t)32 * 98304);
    k5_pv<<<32 * 50, 64, 0, stream>>>(E, phiZ, yv, ypz, 32);

    k6b_ycomb<<<32, 256, 0, stream>>>(ypz, yzi);
    k7_final<<<64 * 50, 256, 0, stream>>>(yv, yzi, Wbf, Wb, x, bng, bnb, bnm, bnv, out);
}

// Round 13
// 318.459 us; speedup vs baseline: 1.0730x; 1.0432x over previous
//
#include <hip/hip_runtime.h>

#define NTB 25

typedef float f32x4 __attribute__((ext_vector_type(4)));
typedef short bf16x8 __attribute__((ext_vector_type(8)));

__device__ __forceinline__ ushort f2bf(float f) {
    union { float f; uint u; } v; v.f = f;
    uint u = v.u;
    return (ushort)((u + 0x7fffu + ((u >> 16) & 1u)) >> 16);
}
__device__ __forceinline__ float bf2f(ushort h) {
    union { uint u; float f; } v; v.u = ((uint)h) << 16;
    return v.f;
}
// fragment-block element offset: element (p, k32) of a 16x32 tile stored
// so that lane l owns u16 slots l*8..l*8+7 = (p=l&15, k=(l>>4)*8+j).
__device__ __forceinline__ int foff(int p, int k32) {
    return (((p & 15) | (((k32 >> 3) & 3) << 4)) << 3) + (k32 & 7);
}

// ---------------- K0: weights f32 -> frag-swizzled bf16 ----------------
__global__ __launch_bounds__(256) void k0_wconv(
    const float* __restrict__ gw, const float* __restrict__ tw,
    const float* __restrict__ Ww,
    ushort* __restrict__ gwb, ushort* __restrict__ twb, ushort* __restrict__ Wbf)
{
    int idx = blockIdx.x * 256 + threadIdx.x;
    if (idx < 8192) {
        const float* src = (idx < 4096) ? gw : tw;
        ushort* dst = (idx < 4096) ? gwb : twb;
        int u = idx & 4095;
        int o = u >> 5, c0 = (u & 31) << 3;
        ushort* d = dst + ((o >> 4) * 8 + (c0 >> 5)) * 512 + foff(o, c0 & 31);
        #pragma unroll
        for (int j = 0; j < 8; ++j) d[j] = f2bf(src[o * 256 + c0 + j]);
    } else if (idx < 12288) {
        int u = idx - 8192;
        int o = u >> 4, c0 = (u & 15) << 3;
        ushort* d = Wbf + ((o >> 4) * 4 + (c0 >> 5)) * 512 + foff(o, c0 & 31);
        #pragma unroll
        for (int j = 0; j < 8; ++j) d[j] = f2bf(Ww[o * 128 + c0 + j]);
    }
}

// ---------------- K1a: x f32[b][c][n] -> xT frag-swizzled bf16 (rows n, k c) ----------------
__global__ __launch_bounds__(256) void k1a_xpose(const float* __restrict__ x,
                                                 ushort* __restrict__ xT)
{
    int blk = blockIdx.x;
    int nt = blk % NTB; blk /= NTB;
    int cb = blk & 3; int b = blk >> 2;
    int n0 = nt * 64, c0 = cb * 64;
    __shared__ ushort lds[64 * 70];
    int tid = threadIdx.x;

    const float* xb = x + ((size_t)b * 256 + c0) * 1600 + n0;
    #pragma unroll
    for (int p = 0; p < 4; ++p) {
        int idx = tid + p * 256;
        int c = idx >> 4, n4 = idx & 15;
        float4 v = *reinterpret_cast<const float4*>(&xb[(size_t)c * 1600 + n4 * 4]);
        ushort4 pk;
        pk.x = f2bf(v.x); pk.y = f2bf(v.y); pk.z = f2bf(v.z); pk.w = f2bf(v.w);
        *reinterpret_cast<ushort4*>(&lds[c * 70 + n4 * 4]) = pk;
    }
    __syncthreads();
    #pragma unroll
    for (int q = 0; q < 2; ++q) {
        int t2 = tid + q * 256;
        int nl = t2 >> 3, c8 = t2 & 7;
        int n = n0 + nl, c = c0 + c8 * 8;
        bf16x8 r;
        #pragma unroll
        for (int j = 0; j < 8; ++j)
            r[j] = (short)lds[(c8 * 8 + j) * 70 + nl];
        *reinterpret_cast<bf16x8*>(
            &xT[(size_t)b * 409600 + (size_t)((n >> 4) * 8 + (c >> 5)) * 512 +
                foff(n, c & 31)]) = r;
    }
}

// ---------------- K1b: barrier-free dual conv1x1, all-frag operands ----------------
__global__ __launch_bounds__(256) void k1b_conv(
    const ushort* __restrict__ xT,
    const ushort* __restrict__ gwb, const float* __restrict__ gb,
    const ushort* __restrict__ twb, const float* __restrict__ tb,
    ushort* __restrict__ gout, ushort* __restrict__ thT)
{
    int nt = blockIdx.x % NTB, b = blockIdx.x / NTB;
    int n0 = nt * 64;
    int tid = threadIdx.x, lane = tid & 63, w = tid >> 6;
    int lr = lane & 15, lg = lane >> 4;
    const ushort* xb = xT + (size_t)b * 409600;

    if (w < 2) {
        int o0 = w * 64;
        f32x4 acc[4][4] = {};
        #pragma unroll
        for (int kc = 0; kc < 8; ++kc) {
            bf16x8 a[4], bf[4];
            #pragma unroll
            for (int mi = 0; mi < 4; ++mi)
                a[mi] = *reinterpret_cast<const bf16x8*>(
                    &xb[(size_t)(((n0 >> 4) + mi) * 8 + kc) * 512 + lane * 8]);
            #pragma unroll
            for (int ni = 0; ni < 4; ++ni)
                bf[ni] = *reinterpret_cast<const bf16x8*>(
                    &gwb[(size_t)(((o0 >> 4) + ni) * 8 + kc) * 512 + lane * 8]);
            #pragma unroll
            for (int mi = 0; mi < 4; ++mi)
                #pragma unroll
                for (int ni = 0; ni < 4; ++ni)
                    acc[mi][ni] = __builtin_amdgcn_mfma_f32_16x16x32_bf16(
                        a[mi], bf[ni], acc[mi][ni], 0, 0, 0);
        }
        #pragma unroll
        for (int ni = 0; ni < 4; ++ni) {
            int o = o0 + ni * 16 + lr;
            float bs = gb[o];
            ushort* gp = &gout[((size_t)b * 128 + o) * 1600 + n0];
            #pragma unroll
            for (int mi = 0; mi < 4; ++mi) {
                ushort4 pk;
                pk.x = f2bf(acc[mi][ni][0] + bs);
                pk.y = f2bf(acc[mi][ni][1] + bs);
                pk.z = f2bf(acc[mi][ni][2] + bs);
                pk.w = f2bf(acc[mi][ni][3] + bs);
                *reinterpret_cast<ushort4*>(&gp[mi * 16 + lg * 4]) = pk;
            }
        }
    } else {
        int o0 = (w - 2) * 64;
        f32x4 acc[4][4] = {};
        #pragma unroll
        for (int kc = 0; kc < 8; ++kc) {
            bf16x8 a[4], bf[4];
            #pragma unroll
            for (int mi = 0; mi < 4; ++mi)
                a[mi] = *reinterpret_cast<const bf16x8*>(
                    &twb[(size_t)(((o0 >> 4) + mi) * 8 + kc) * 512 + lane * 8]);
            #pragma unroll
            for (int ni = 0; ni < 4; ++ni)
                bf[ni] = *reinterpret_cast<const bf16x8*>(
                    &xb[(size_t)(((n0 >> 4) + ni) * 8 + kc) * 512 + lane * 8]);
            #pragma unroll
            for (int mi = 0; mi < 4; ++mi)
                #pragma unroll
                for (int ni = 0; ni < 4; ++ni)
                    acc[mi][ni] = __builtin_amdgcn_mfma_f32_16x16x32_bf16(
                        a[mi], bf[ni], acc[mi][ni], 0, 0, 0);
        }
        #pragma unroll
        for (int mi = 0; mi < 4; ++mi) {
            float4 tbv = *reinterpret_cast<const float4*>(&tb[o0 + mi * 16 + lg * 4]);
            float tbb[4] = {tbv.x, tbv.y, tbv.z, tbv.w};
            int cq = o0 + mi * 16 + lg * 4;
            #pragma unroll
            for (int ni = 0; ni < 4; ++ni) {
                int n = n0 + ni * 16 + lr;
                ushort4 pk;
                pk.x = f2bf(acc[mi][ni][0] + tbb[0]);
                pk.y = f2bf(acc[mi][ni][1] + tbb[1]);
                pk.z = f2bf(acc[mi][ni][2] + tbb[2]);
                pk.w = f2bf(acc[mi][ni][3] + tbb[3]);
                *reinterpret_cast<ushort4*>(
                    &thT[(size_t)b * 204800 + (size_t)((n >> 4) * 4 + (cq >> 5)) * 512 +
                         foff(n, cq & 31)]) = pk;
            }
        }
    }
}

// ---------------- K2: PSP pooling v3 (direct-global row reads, coalesced writes) ----------------
__global__ __launch_bounds__(256) void k2a_psp(const ushort* __restrict__ g,
                                               ushort* __restrict__ phiC,
                                               ushort* __restrict__ phiT)
{
    int cc = blockIdx.x & 7, b = blockIdx.x >> 3;
    __shared__ ushort pooled[16][776];
    int tid = threadIdx.x;

    #pragma unroll
    for (int it = 0; it < 2; ++it) {
        int item = tid + it * 256;
        if (item < 400) {
            int cl = item / 25, r = item % 25;
            const ushort* gp = g + ((size_t)((b * 128 + cc * 16 + cl) * 25 + r)) * 64;
            float S4[16];
            #pragma unroll
            for (int q = 0; q < 8; ++q) {
                bf16x8 v = *reinterpret_cast<const bf16x8*>(&gp[q * 8]);
                S4[q * 2]     = bf2f((ushort)v[0]) + bf2f((ushort)v[1]) +
                                bf2f((ushort)v[2]) + bf2f((ushort)v[3]);
                S4[q * 2 + 1] = bf2f((ushort)v[4]) + bf2f((ushort)v[5]) +
                                bf2f((ushort)v[6]) + bf2f((ushort)v[7]);
            }
            float S8[8], S16[4];
            float tot = 0.f;
            #pragma unroll
            for (int k = 0; k < 8; ++k) S8[k] = S4[2 * k] + S4[2 * k + 1];
            #pragma unroll
            for (int k = 0; k < 4; ++k) { S16[k] = S8[2 * k] + S8[2 * k + 1]; tot += S16[k]; }
            ushort* row = pooled[cl];
            row[r] = f2bf(tot * (1.f / 64.f));
            #pragma unroll
            for (int k = 0; k < 4; ++k)  row[25 + 4 * r + k]  = f2bf(S16[k] * 0.0625f);
            #pragma unroll
            for (int k = 0; k < 8; ++k)  row[125 + 8 * r + k] = f2bf(S8[k] * 0.125f);
            #pragma unroll
            for (int k = 0; k < 16; ++k) row[325 + 16 * r + k] = f2bf(S4[k] * 0.25f);
        }
    }
    if (tid < 16) {
        ushort* row = pooled[tid];
        for (int j = 725; j < 768; ++j) row[j] = 0;
    }
    __syncthreads();

    {
        ushort* pc = phiC + (size_t)(b * 128 + cc * 16) * 768;
        #pragma unroll
        for (int i = 0; i < 6; ++i) {
            int q = tid + i * 256;
            int cl = q / 96, j8 = (q % 96) * 8;
            bf16x8 v = *reinterpret_cast<const bf16x8*>(&pooled[cl][j8]);
            *reinterpret_cast<bf16x8*>(&pc[(size_t)cl * 768 + j8]) = v;
        }
    }
    {
        ushort* pt = phiT + (size_t)b * 98304 + (size_t)(cc >> 1) * 512 + (cc & 1) * 256;
        #pragma unroll
        for (int i = 0; i < 6; ++i) {
            int slot = tid + i * 256;
            int jt = slot >> 5, lh = slot & 31;
            int jl = jt * 16 + (lh & 15);
            int cb8 = (lh >> 4) * 8;
            bf16x8 v;
            #pragma unroll
            for (int jj = 0; jj < 8; ++jj)
                v[jj] = (short)pooled[cb8 + jj][jl];
            *reinterpret_cast<bf16x8*>(&pt[(size_t)(jt * 4) * 512 + lh * 8]) = v;
        }
    }
}

// ---------------- K3: E = exp(theta^T phi) + column-sum partials ----------------
// psum PLANE-MAJOR: psum[nt][b][s].
__global__ __launch_bounds__(256) void k3_expf(
    const ushort* __restrict__ thT, const ushort* __restrict__ phiT,
    ushort* __restrict__ E, float* __restrict__ psum, int b0)
{
    int blk = blockIdx.x;
    int st = blk % 12; blk /= 12;
    int nt = blk % 25; int bl = blk / 25;
    int b = b0 + bl;
    int n0 = nt * 64, s0 = st * 64;
    int tid = threadIdx.x, lane = tid & 63, w = tid >> 6;
    int lr = lane & 15, lg = lane >> 4;

    __shared__ ushort Bs[8192];
    __shared__ float red[64][4];

    {
        const ushort* src = phiT + (size_t)b * 98304 + (size_t)(s0 >> 4) * 2048;
        #pragma unroll
        for (int t = 0; t < 4; ++t) {
            int o8 = (t * 256 + tid) * 8;
            *reinterpret_cast<bf16x8*>(&Bs[o8]) =
                *reinterpret_cast<const bf16x8*>(&src[o8]);
        }
    }
    bf16x8 A[4];
    #pragma unroll
    for (int kc = 0; kc < 4; ++kc)
        A[kc] = *reinterpret_cast<const bf16x8*>(
            &thT[(size_t)b * 204800 + (size_t)(((n0 >> 4) + w) * 4 + kc) * 512 + lane * 8]);
    __syncthreads();

    f32x4 acc[4] = {};
    #pragma unroll
    for (int kc = 0; kc < 4; ++kc)
        #pragma unroll
        for (int ni = 0; ni < 4; ++ni) {
            bf16x8 bb = *reinterpret_cast<const bf16x8*>(&Bs[(ni * 4 + kc) * 512 + lane * 8]);
            acc[ni] = __builtin_amdgcn_mfma_f32_16x16x32_bf16(A[kc], bb, acc[ni], 0, 0, 0);
        }

    size_t ebase = (size_t)bl * 1228800 + (size_t)(((n0 >> 4) + w) * 24 + (s0 >> 5)) * 512;
    #pragma unroll
    for (int ni = 0; ni < 4; ++ni) {
        float se = 0.f;
        float ex[4];
        #pragma unroll
        for (int r = 0; r < 4; ++r) { ex[r] = __expf(acc[ni][r]); se += ex[r]; }
        int scadd = (ni >> 1) * 512;
        int khi = ((ni & 1) * 2 + (lr >> 3)) & 3;
        #pragma unroll
        for (int r = 0; r < 4; ++r) {
            int p = lg * 4 + r;
            E[ebase + scadd + ((p | (khi << 4)) << 3) + (lr & 7)] = f2bf(ex[r]);
        }
        se += __shfl_xor(se, 16);
        se += __shfl_xor(se, 32);
        if (lg == 0) red[ni * 16 + lr][w] = se;
    }
    __syncthreads();
    if (tid < 64) {
        float z = red[tid][0] + red[tid][1] + red[tid][2] + red[tid][3];
        psum[(size_t)nt * 49152 + (size_t)b * 768 + s0 + tid] = z;
    }
}

// ---------------- K4a: zinv[bh][s] = 1/sum over nt planes ----------------
__global__ __launch_bounds__(256) void k4a_zinv(const float* __restrict__ psum,
                                                float* __restrict__ zinv, int b0)
{
    int idx = blockIdx.x * 256 + threadIdx.x;
    if (idx >= 32 * 768) return;
    int s = idx % 768, bh = idx / 768;
    size_t base = (size_t)(b0 + bh) * 768 + s;
    float z = 0.f;
    #pragma unroll
    for (int i = 0; i < 25; ++i) z += psum[(size_t)i * 49152 + base];
    zinv[idx] = (s < 725) ? 1.f / z : 0.f;
}

// ---------------- K4b: phiZ frag-blocks = phiC * zinv, fully coalesced ----------------
__global__ __launch_bounds__(256) void k4b_scale(const ushort* __restrict__ phiC,
                                                 const float* __restrict__ zinv,
                                                 ushort* __restrict__ phiZ)
{
    int idx = blockIdx.x * 256 + threadIdx.x;
    int l = idx & 63;
    int t = idx >> 6;
    int bi = t % 192, b = t / 192;
    int c = (bi / 24) * 16 + (l & 15);
    int s0 = (bi % 24) * 32 + (l >> 4) * 8;
    bf16x8 v = *reinterpret_cast<const bf16x8*>(&phiC[((size_t)b * 128 + c) * 768 + s0]);
    float4 z0 = *reinterpret_cast<const float4*>(&zinv[b * 768 + s0]);
    float4 z1 = *reinterpret_cast<const float4*>(&zinv[b * 768 + s0 + 4]);
    float zz[8] = {z0.x, z0.y, z0.z, z0.w, z1.x, z1.y, z1.z, z1.w};
    bf16x8 r;
    #pragma unroll
    for (int j = 0; j < 8; ++j) r[j] = (short)f2bf(bf2f((ushort)v[j]) * zz[j]);
    *reinterpret_cast<bf16x8*>(&phiZ[(size_t)b * 98304 + (size_t)bi * 512 + l * 8]) = r;
}

// ---------------- K5: y = E @ phiZ^T, 32 rows/wave, depth-3 prefetch ----------------
__global__ __launch_bounds__(64, 2) void k5_pv(
    const ushort* __restrict__ E, const ushort* __restrict__ phiZ,
    ushort* __restrict__ y, float* __restrict__ ypz, int b0)
{
    int ng2 = blockIdx.x % 50, bl = blockIdx.x / 50;
    int b = b0 + bl;
    int lane = threadIdx.x;
    int lr = lane & 15, lg = lane >> 4;
    const ushort* Eb = E + (size_t)bl * 1228800 + (size_t)(ng2 * 2) * 24 * 512 + lane * 8;
    const ushort* Pb = phiZ + (size_t)b * 98304 + lane * 8;

    f32x4 acc[2][8] = {};
    bf16x8 Ab[3][2], Bb[3][8];
    #pragma unroll
    for (int p = 0; p < 3; ++p) {
        Ab[p][0] = *reinterpret_cast<const bf16x8*>(&Eb[(size_t)p * 512]);
        Ab[p][1] = *reinterpret_cast<const bf16x8*>(&Eb[(size_t)(24 + p) * 512]);
        #pragma unroll
        for (int cf = 0; cf < 8; ++cf)
            Bb[p][cf] = *reinterpret_cast<const bf16x8*>(&Pb[(size_t)(cf * 24 + p) * 512]);
    }
    #pragma unroll
    for (int kc = 0; kc < 24; ++kc) {
        int cur = kc % 3;
        bf16x8 a0 = Ab[cur][0], a1 = Ab[cur][1];
        #pragma unroll
        for (int cf = 0; cf < 8; ++cf) {
            bf16x8 bbv = Bb[cur][cf];
            acc[0][cf] = __builtin_amdgcn_mfma_f32_16x16x32_bf16(a0, bbv, acc[0][cf], 0, 0, 0);
            acc[1][cf] = __builtin_amdgcn_mfma_f32_16x16x32_bf16(a1, bbv, acc[1][cf], 0, 0, 0);
        }
        if (kc + 3 < 24) {
            Ab[cur][0] = *reinterpret_cast<const bf16x8*>(&Eb[(size_t)(kc + 3) * 512]);
            Ab[cur][1] = *reinterpret_cast<const bf16x8*>(&Eb[(size_t)(24 + kc + 3) * 512]);
            #pragma unroll
            for (int cf = 0; cf < 8; ++cf)
                Bb[cur][cf] = *reinterpret_cast<const bf16x8*>(
                    &Pb[(size_t)(cf * 24 + kc + 3) * 512]);
        }
    }

    #pragma unroll
    for (int m = 0; m < 2; ++m) {
        int ng = ng2 * 2 + m;
        int nrow = ng * 16;
        #pragma unroll
        for (int cf = 0; cf < 8; ++cf) {
            float se = 0.f;
            #pragma unroll
            for (int r = 0; r < 4; ++r) {
                ushort hv = f2bf(acc[m][cf][r]);
                y[((size_t)b * 1600 + nrow + lg * 4 + r) * 128 + cf * 16 + lr] = hv;
                se += __expf(bf2f(hv));
            }
            se += __shfl_xor(se, 16);
            se += __shfl_xor(se, 32);
            if (lane < 16)
                ypz[((size_t)ng * 64 + b) * 128 + cf * 16 + lane] = se;
        }
    }
}

// ---------------- K6b: combine 100 plane-major partials -> 1/Z2 per (b,c) ----------------
__global__ void k6b_ycomb(const float* __restrict__ ypz, float* __restrict__ yzi)
{
    int idx = blockIdx.x * 256 + threadIdx.x;
    if (idx >= 64 * 128) return;
    float z = 0.f;
    for (int ng = 0; ng < 100; ++ng) z += ypz[(size_t)ng * 8192 + idx];
    yzi[idx] = 1.f / z;
}

// ---------------- K7: softmax(y) -> conv W + residual + BN + ReLU ----------------
// round-10 structure (64n x 256o, best measured); NT store on out only.
__global__ __launch_bounds__(256) void k7_final(
    const ushort* __restrict__ y, const float* __restrict__ yzi,
    const ushort* __restrict__ Wbf, const float* __restrict__ Wb,
    const float* __restrict__ x,
    const float* __restrict__ gamma, const float* __restrict__ beta,
    const float* __restrict__ mean, const float* __restrict__ var,
    float* __restrict__ out)
{
    int nt = blockIdx.x % NTB, b = blockIdx.x / NTB;
    int n0 = nt * 64;
    __shared__ ushort yl[64][136];
    __shared__ float scl[256], shl[256], wbl[256], zl[128];
    int t = threadIdx.x, lane = t & 63, w = t >> 6;
    {
        float sc = gamma[t] * rsqrtf(var[t] + 1e-5f);
        scl[t] = sc;
        shl[t] = beta[t] - mean[t] * sc;
        wbl[t] = Wb[t];
        if (t < 128) zl[t] = yzi[(size_t)b * 128 + t];
    }
    __syncthreads();
    int c8 = (t & 15) * 8, rr = t >> 4;
    #pragma unroll
    for (int p = 0; p < 4; ++p) {
        int r = rr + 16 * p;
        bf16x8 v = *reinterpret_cast<const bf16x8*>(
            &y[((size_t)b * 1600 + n0 + r) * 128 + c8]);
        bf16x8 pk;
        #pragma unroll
        for (int j = 0; j < 8; ++j) {
            float f = bf2f((ushort)v[j]);
            pk[j] = (short)f2bf(__expf(f) * zl[c8 + j]);
        }
        *reinterpret_cast<bf16x8*>(&yl[r][c8]) = pk;
    }
    __syncthreads();
    int lr = lane & 15, lg = lane >> 4;
    int o0 = w * 64;
    f32x4 acc[4][4] = {};
    #pragma unroll
    for (int kc = 0; kc < 4; ++kc) {
        bf16x8 af[4];
        #pragma unroll
        for (int mi = 0; mi < 4; ++mi)
            af[mi] = *reinterpret_cast<const bf16x8*>(
                &Wbf[(size_t)(((o0 >> 4) + mi) * 4 + kc) * 512 + lane * 8]);
        #pragma unroll
        for (int ni = 0; ni < 4; ++ni) {
            bf16x8 bfrag = *reinterpret_cast<const bf16x8*>(&yl[ni * 16 + lr][kc * 32 + lg * 8]);
            #pragma unroll
            for (int mi = 0; mi < 4; ++mi)
                acc[mi][ni] = __builtin_amdgcn_mfma_f32_16x16x32_bf16(
                    af[mi], bfrag, acc[mi][ni], 0, 0, 0);
        }
    }
    #pragma unroll
    for (int mi = 0; mi < 4; ++mi)
        #pragma unroll
        for (int ni = 0; ni < 4; ++ni) {
            int n = n0 + ni * 16 + lr;
            #pragma unroll
            for (int r = 0; r < 4; ++r) {
                int o = o0 + mi * 16 + lg * 4 + r;
                size_t off = ((size_t)b * 256 + o) * 1600 + n;
                float v = (acc[mi][ni][r] + wbl[o] + x[off]) * scl[o] + shl[o];
                __builtin_nontemporal_store(fmaxf(v, 0.f), &out[off]);
            }
        }
}

extern "C" void kernel_launch(void* const* d_in, const int* in_sizes, int n_in,
                              void* d_out, int out_size, void* d_ws, size_t ws_size,
                              hipStream_t stream)
{
    const float* x   = (const float*)d_in[0];
    const float* gw  = (const float*)d_in[1];
    const float* gb  = (const float*)d_in[2];
    const float* tw  = (const float*)d_in[3];
    const float* tb  = (const float*)d_in[4];
    const float* Ww  = (const float*)d_in[5];
    const float* Wb  = (const float*)d_in[6];
    const float* bng = (const float*)d_in[7];
    const float* bnb = (const float*)d_in[8];
    const float* bnm = (const float*)d_in[9];
    const float* bnv = (const float*)d_in[10];
    float* out = (float*)d_out;

    char* base = (char*)d_ws;
    ushort* thT  = (ushort*)(base);               // 26,214,400 B (frag-swz)
    ushort* gout = (ushort*)(base + 26214400);    // 26,214,400 B (reused as y)
    ushort* phiC = (ushort*)(base + 52428800);    // 12,582,912 B (row-major)
    ushort* phiT = (ushort*)(base + 65011712);    // 12,582,912 B (frag-swz)
    float* psum  = (float*)(base + 77594624);     //  4,915,200 B  [nt][b][s]
    ushort* phiZ = (ushort*)(base + 82509824);    // 12,582,912 B (frag-swz)
    float* zinv  = (float*)(base + 95092736);     //    196,608 B
    float* ypz   = (float*)(base + 95289344);     //  3,276,800 B  [ng][b][c]
    float* yzi   = (float*)(base + 98566144);     //     32,768 B
    ushort* Wbf  = (ushort*)(base + 98598912);    //     65,536 B (frag-swz)
    ushort* gwb  = (ushort*)(base + 98664448);    //     65,536 B (frag-swz)
    ushort* twb  = (ushort*)(base + 98729984);    //     65,536 B (frag-swz)
    ushort* yv   = gout;                          // alias: gout dead after k2a
    ushort* xT   = (ushort*)d_out;                // scratch in out region
    ushort* E    = (ushort*)d_out;

    k0_wconv<<<48, 256, 0, stream>>>(gw, tw, Ww, gwb, twb, Wbf);
    k1a_xpose<<<64 * 4 * NTB, 256, 0, stream>>>(x, xT);
    k1b_conv<<<64 * NTB, 256, 0, stream>>>(xT, gwb, gb, twb, tb, gout, thT);
    k2a_psp<<<64 * 8, 256, 0, stream>>>(gout, phiC, phiT);

    // half 0: batches 0..31
    k3_expf<<<32 * 25 * 12, 256, 0, stream>>>(thT, phiT, E, psum, 0);
    k4a_zinv<<<96, 256, 0, stream>>>(psum, zinv, 0);
    k4b_scale<<<1536, 256, 0, stream>>>(phiC, zinv, phiZ);
    k5_pv<<<32 * 50, 64, 0, stream>>>(E, phiZ, yv, ypz, 0);

    // half 1: batches 32..63
    k3_expf<<<32 * 25 * 12, 256, 0, stream>>>(thT, phiT, E, psum, 32);
    k4a_zinv<<<96, 256, 0, stream>>>(psum, zinv, 32);
    k4b_scale<<<1536, 256, 0, stream>>>(phiC + (size_t)32 * 128 * 768, zinv,
                                        phiZ + (size_t)32 * 98304);
    k5_pv<<<32 * 50, 64, 0, stream>>>(E, phiZ, yv, ypz, 32);

    k6b_ycomb<<<32, 256, 0, stream>>>(ypz, yzi);
    k7_final<<<64 * NTB, 256, 0, stream>>>(yv, yzi, Wbf, Wb, x, bng, bnb, bnm, bnv, out);
}

// Round 14
// 303.484 us; speedup vs baseline: 1.1260x; 1.0493x over previous
//
#include <hip/hip_runtime.h>

#define NTB 25

typedef float f32x4 __attribute__((ext_vector_type(4)));
typedef short bf16x8 __attribute__((ext_vector_type(8)));

__device__ __forceinline__ ushort f2bf(float f) {
    union { float f; uint u; } v; v.f = f;
    uint u = v.u;
    return (ushort)((u + 0x7fffu + ((u >> 16) & 1u)) >> 16);
}
__device__ __forceinline__ float bf2f(ushort h) {
    union { uint u; float f; } v; v.u = ((uint)h) << 16;
    return v.f;
}
// fragment-block element offset: element (p, k32) of a 16x32 tile stored
// so that lane l owns u16 slots l*8..l*8+7 = (p=l&15, k=(l>>4)*8+j).
__device__ __forceinline__ int foff(int p, int k32) {
    return (((p & 15) | (((k32 >> 3) & 3) << 4)) << 3) + (k32 & 7);
}

// ---------------- K0: weights f32 -> frag-swizzled bf16 ----------------
__global__ __launch_bounds__(256) void k0_wconv(
    const float* __restrict__ gw, const float* __restrict__ tw,
    const float* __restrict__ Ww,
    ushort* __restrict__ gwb, ushort* __restrict__ twb, ushort* __restrict__ Wbf)
{
    int idx = blockIdx.x * 256 + threadIdx.x;
    if (idx < 8192) {
        const float* src = (idx < 4096) ? gw : tw;
        ushort* dst = (idx < 4096) ? gwb : twb;
        int u = idx & 4095;
        int o = u >> 5, c0 = (u & 31) << 3;
        ushort* d = dst + ((o >> 4) * 8 + (c0 >> 5)) * 512 + foff(o, c0 & 31);
        #pragma unroll
        for (int j = 0; j < 8; ++j) d[j] = f2bf(src[o * 256 + c0 + j]);
    } else if (idx < 12288) {
        int u = idx - 8192;
        int o = u >> 4, c0 = (u & 15) << 3;
        ushort* d = Wbf + ((o >> 4) * 4 + (c0 >> 5)) * 512 + foff(o, c0 & 31);
        #pragma unroll
        for (int j = 0; j < 8; ++j) d[j] = f2bf(Ww[o * 128 + c0 + j]);
    }
}

// ---------------- K1a: x f32[b][c][n] -> xT frag-swizzled bf16 (rows n, k c) ----------------
__global__ __launch_bounds__(256) void k1a_xpose(const float* __restrict__ x,
                                                 ushort* __restrict__ xT)
{
    int blk = blockIdx.x;
    int nt = blk % NTB; blk /= NTB;
    int cb = blk & 3; int b = blk >> 2;
    int n0 = nt * 64, c0 = cb * 64;
    __shared__ ushort lds[64 * 70];
    int tid = threadIdx.x;

    const float* xb = x + ((size_t)b * 256 + c0) * 1600 + n0;
    #pragma unroll
    for (int p = 0; p < 4; ++p) {
        int idx = tid + p * 256;
        int c = idx >> 4, n4 = idx & 15;
        float4 v = *reinterpret_cast<const float4*>(&xb[(size_t)c * 1600 + n4 * 4]);
        ushort4 pk;
        pk.x = f2bf(v.x); pk.y = f2bf(v.y); pk.z = f2bf(v.z); pk.w = f2bf(v.w);
        *reinterpret_cast<ushort4*>(&lds[c * 70 + n4 * 4]) = pk;
    }
    __syncthreads();
    #pragma unroll
    for (int q = 0; q < 2; ++q) {
        int t2 = tid + q * 256;
        int nl = t2 >> 3, c8 = t2 & 7;
        int n = n0 + nl, c = c0 + c8 * 8;
        bf16x8 r;
        #pragma unroll
        for (int j = 0; j < 8; ++j)
            r[j] = (short)lds[(c8 * 8 + j) * 70 + nl];
        *reinterpret_cast<bf16x8*>(
            &xT[(size_t)b * 409600 + (size_t)((n >> 4) * 8 + (c >> 5)) * 512 +
                foff(n, c & 31)]) = r;
    }
}

// ---------------- K1b: barrier-free dual conv1x1, all-frag operands ----------------
__global__ __launch_bounds__(256) void k1b_conv(
    const ushort* __restrict__ xT,
    const ushort* __restrict__ gwb, const float* __restrict__ gb,
    const ushort* __restrict__ twb, const float* __restrict__ tb,
    ushort* __restrict__ gout, ushort* __restrict__ thT)
{
    int nt = blockIdx.x % NTB, b = blockIdx.x / NTB;
    int n0 = nt * 64;
    int tid = threadIdx.x, lane = tid & 63, w = tid >> 6;
    int lr = lane & 15, lg = lane >> 4;
    const ushort* xb = xT + (size_t)b * 409600;

    if (w < 2) {
        int o0 = w * 64;
        f32x4 acc[4][4] = {};
        #pragma unroll
        for (int kc = 0; kc < 8; ++kc) {
            bf16x8 a[4], bf[4];
            #pragma unroll
            for (int mi = 0; mi < 4; ++mi)
                a[mi] = *reinterpret_cast<const bf16x8*>(
                    &xb[(size_t)(((n0 >> 4) + mi) * 8 + kc) * 512 + lane * 8]);
            #pragma unroll
            for (int ni = 0; ni < 4; ++ni)
                bf[ni] = *reinterpret_cast<const bf16x8*>(
                    &gwb[(size_t)(((o0 >> 4) + ni) * 8 + kc) * 512 + lane * 8]);
            #pragma unroll
            for (int mi = 0; mi < 4; ++mi)
                #pragma unroll
                for (int ni = 0; ni < 4; ++ni)
                    acc[mi][ni] = __builtin_amdgcn_mfma_f32_16x16x32_bf16(
                        a[mi], bf[ni], acc[mi][ni], 0, 0, 0);
        }
        #pragma unroll
        for (int ni = 0; ni < 4; ++ni) {
            int o = o0 + ni * 16 + lr;
            float bs = gb[o];
            ushort* gp = &gout[((size_t)b * 128 + o) * 1600 + n0];
            #pragma unroll
            for (int mi = 0; mi < 4; ++mi) {
                ushort4 pk;
                pk.x = f2bf(acc[mi][ni][0] + bs);
                pk.y = f2bf(acc[mi][ni][1] + bs);
                pk.z = f2bf(acc[mi][ni][2] + bs);
                pk.w = f2bf(acc[mi][ni][3] + bs);
                *reinterpret_cast<ushort4*>(&gp[mi * 16 + lg * 4]) = pk;
            }
        }
    } else {
        int o0 = (w - 2) * 64;
        f32x4 acc[4][4] = {};
        #pragma unroll
        for (int kc = 0; kc < 8; ++kc) {
            bf16x8 a[4], bf[4];
            #pragma unroll
            for (int mi = 0; mi < 4; ++mi)
                a[mi] = *reinterpret_cast<const bf16x8*>(
                    &twb[(size_t)(((o0 >> 4) + mi) * 8 + kc) * 512 + lane * 8]);
            #pragma unroll
            for (int ni = 0; ni < 4; ++ni)
                bf[ni] = *reinterpret_cast<const bf16x8*>(
                    &xb[(size_t)(((n0 >> 4) + ni) * 8 + kc) * 512 + lane * 8]);
            #pragma unroll
            for (int mi = 0; mi < 4; ++mi)
                #pragma unroll
                for (int ni = 0; ni < 4; ++ni)
                    acc[mi][ni] = __builtin_amdgcn_mfma_f32_16x16x32_bf16(
                        a[mi], bf[ni], acc[mi][ni], 0, 0, 0);
        }
        #pragma unroll
        for (int mi = 0; mi < 4; ++mi) {
            float4 tbv = *reinterpret_cast<const float4*>(&tb[o0 + mi * 16 + lg * 4]);
            float tbb[4] = {tbv.x, tbv.y, tbv.z, tbv.w};
            int cq = o0 + mi * 16 + lg * 4;
            #pragma unroll
            for (int ni = 0; ni < 4; ++ni) {
                int n = n0 + ni * 16 + lr;
                ushort4 pk;
                pk.x = f2bf(acc[mi][ni][0] + tbb[0]);
                pk.y = f2bf(acc[mi][ni][1] + tbb[1]);
                pk.z = f2bf(acc[mi][ni][2] + tbb[2]);
                pk.w = f2bf(acc[mi][ni][3] + tbb[3]);
                *reinterpret_cast<ushort4*>(
                    &thT[(size_t)b * 204800 + (size_t)((n >> 4) * 4 + (cq >> 5)) * 512 +
                         foff(n, cq & 31)]) = pk;
            }
        }
    }
}

// ---------------- K2: PSP pooling v3 (direct-global row reads, coalesced writes) ----------------
__global__ __launch_bounds__(256) void k2a_psp(const ushort* __restrict__ g,
                                               ushort* __restrict__ phiC,
                                               ushort* __restrict__ phiT)
{
    int cc = blockIdx.x & 7, b = blockIdx.x >> 3;
    __shared__ ushort pooled[16][776];
    int tid = threadIdx.x;

    #pragma unroll
    for (int it = 0; it < 2; ++it) {
        int item = tid + it * 256;
        if (item < 400) {
            int cl = item / 25, r = item % 25;
            const ushort* gp = g + ((size_t)((b * 128 + cc * 16 + cl) * 25 + r)) * 64;
            float S4[16];
            #pragma unroll
            for (int q = 0; q < 8; ++q) {
                bf16x8 v = *reinterpret_cast<const bf16x8*>(&gp[q * 8]);
                S4[q * 2]     = bf2f((ushort)v[0]) + bf2f((ushort)v[1]) +
                                bf2f((ushort)v[2]) + bf2f((ushort)v[3]);
                S4[q * 2 + 1] = bf2f((ushort)v[4]) + bf2f((ushort)v[5]) +
                                bf2f((ushort)v[6]) + bf2f((ushort)v[7]);
            }
            float S8[8], S16[4];
            float tot = 0.f;
            #pragma unroll
            for (int k = 0; k < 8; ++k) S8[k] = S4[2 * k] + S4[2 * k + 1];
            #pragma unroll
            for (int k = 0; k < 4; ++k) { S16[k] = S8[2 * k] + S8[2 * k + 1]; tot += S16[k]; }
            ushort* row = pooled[cl];
            row[r] = f2bf(tot * (1.f / 64.f));
            #pragma unroll
            for (int k = 0; k < 4; ++k)  row[25 + 4 * r + k]  = f2bf(S16[k] * 0.0625f);
            #pragma unroll
            for (int k = 0; k < 8; ++k)  row[125 + 8 * r + k] = f2bf(S8[k] * 0.125f);
            #pragma unroll
            for (int k = 0; k < 16; ++k) row[325 + 16 * r + k] = f2bf(S4[k] * 0.25f);
        }
    }
    if (tid < 16) {
        ushort* row = pooled[tid];
        for (int j = 725; j < 768; ++j) row[j] = 0;
    }
    __syncthreads();

    {
        ushort* pc = phiC + (size_t)(b * 128 + cc * 16) * 768;
        #pragma unroll
        for (int i = 0; i < 6; ++i) {
            int q = tid + i * 256;
            int cl = q / 96, j8 = (q % 96) * 8;
            bf16x8 v = *reinterpret_cast<const bf16x8*>(&pooled[cl][j8]);
            *reinterpret_cast<bf16x8*>(&pc[(size_t)cl * 768 + j8]) = v;
        }
    }
    {
        ushort* pt = phiT + (size_t)b * 98304 + (size_t)(cc >> 1) * 512 + (cc & 1) * 256;
        #pragma unroll
        for (int i = 0; i < 6; ++i) {
            int slot = tid + i * 256;
            int jt = slot >> 5, lh = slot & 31;
            int jl = jt * 16 + (lh & 15);
            int cb8 = (lh >> 4) * 8;
            bf16x8 v;
            #pragma unroll
            for (int jj = 0; jj < 8; ++jj)
                v[jj] = (short)pooled[cb8 + jj][jl];
            *reinterpret_cast<bf16x8*>(&pt[(size_t)(jt * 4) * 512 + lh * 8]) = v;
        }
    }
}

// ---------------- K3: E = exp(theta^T phi) + column-sum partials ----------------
// psum PLANE-MAJOR: psum[nt][b][s].
__global__ __launch_bounds__(256) void k3_expf(
    const ushort* __restrict__ thT, const ushort* __restrict__ phiT,
    ushort* __restrict__ E, float* __restrict__ psum, int b0)
{
    int blk = blockIdx.x;
    int st = blk % 12; blk /= 12;
    int nt = blk % 25; int bl = blk / 25;
    int b = b0 + bl;
    int n0 = nt * 64, s0 = st * 64;
    int tid = threadIdx.x, lane = tid & 63, w = tid >> 6;
    int lr = lane & 15, lg = lane >> 4;

    __shared__ ushort Bs[8192];
    __shared__ float red[64][4];

    {
        const ushort* src = phiT + (size_t)b * 98304 + (size_t)(s0 >> 4) * 2048;
        #pragma unroll
        for (int t = 0; t < 4; ++t) {
            int o8 = (t * 256 + tid) * 8;
            *reinterpret_cast<bf16x8*>(&Bs[o8]) =
                *reinterpret_cast<const bf16x8*>(&src[o8]);
        }
    }
    bf16x8 A[4];
    #pragma unroll
    for (int kc = 0; kc < 4; ++kc)
        A[kc] = *reinterpret_cast<const bf16x8*>(
            &thT[(size_t)b * 204800 + (size_t)(((n0 >> 4) + w) * 4 + kc) * 512 + lane * 8]);
    __syncthreads();

    f32x4 acc[4] = {};
    #pragma unroll
    for (int kc = 0; kc < 4; ++kc)
        #pragma unroll
        for (int ni = 0; ni < 4; ++ni) {
            bf16x8 bb = *reinterpret_cast<const bf16x8*>(&Bs[(ni * 4 + kc) * 512 + lane * 8]);
            acc[ni] = __builtin_amdgcn_mfma_f32_16x16x32_bf16(A[kc], bb, acc[ni], 0, 0, 0);
        }

    size_t ebase = (size_t)bl * 1228800 + (size_t)(((n0 >> 4) + w) * 24 + (s0 >> 5)) * 512;
    #pragma unroll
    for (int ni = 0; ni < 4; ++ni) {
        float se = 0.f;
        float ex[4];
        #pragma unroll
        for (int r = 0; r < 4; ++r) { ex[r] = __expf(acc[ni][r]); se += ex[r]; }
        int scadd = (ni >> 1) * 512;
        int khi = ((ni & 1) * 2 + (lr >> 3)) & 3;
        #pragma unroll
        for (int r = 0; r < 4; ++r) {
            int p = lg * 4 + r;
            E[ebase + scadd + ((p | (khi << 4)) << 3) + (lr & 7)] = f2bf(ex[r]);
        }
        se += __shfl_xor(se, 16);
        se += __shfl_xor(se, 32);
        if (lg == 0) red[ni * 16 + lr][w] = se;
    }
    __syncthreads();
    if (tid < 64) {
        float z = red[tid][0] + red[tid][1] + red[tid][2] + red[tid][3];
        psum[(size_t)nt * 49152 + (size_t)b * 768 + s0 + tid] = z;
    }
}

// ---------------- K4a: zinv[bh][s] = 1/sum over nt planes ----------------
__global__ __launch_bounds__(256) void k4a_zinv(const float* __restrict__ psum,
                                                float* __restrict__ zinv, int b0)
{
    int idx = blockIdx.x * 256 + threadIdx.x;
    if (idx >= 32 * 768) return;
    int s = idx % 768, bh = idx / 768;
    size_t base = (size_t)(b0 + bh) * 768 + s;
    float z = 0.f;
    #pragma unroll
    for (int i = 0; i < 25; ++i) z += psum[(size_t)i * 49152 + base];
    zinv[idx] = (s < 725) ? 1.f / z : 0.f;
}

// ---------------- K4b: phiZ frag-blocks = phiC * zinv, fully coalesced ----------------
__global__ __launch_bounds__(256) void k4b_scale(const ushort* __restrict__ phiC,
                                                 const float* __restrict__ zinv,
                                                 ushort* __restrict__ phiZ)
{
    int idx = blockIdx.x * 256 + threadIdx.x;
    int l = idx & 63;
    int t = idx >> 6;
    int bi = t % 192, b = t / 192;
    int c = (bi / 24) * 16 + (l & 15);
    int s0 = (bi % 24) * 32 + (l >> 4) * 8;
    bf16x8 v = *reinterpret_cast<const bf16x8*>(&phiC[((size_t)b * 128 + c) * 768 + s0]);
    float4 z0 = *reinterpret_cast<const float4*>(&zinv[b * 768 + s0]);
    float4 z1 = *reinterpret_cast<const float4*>(&zinv[b * 768 + s0 + 4]);
    float zz[8] = {z0.x, z0.y, z0.z, z0.w, z1.x, z1.y, z1.z, z1.w};
    bf16x8 r;
    #pragma unroll
    for (int j = 0; j < 8; ++j) r[j] = (short)f2bf(bf2f((ushort)v[j]) * zz[j]);
    *reinterpret_cast<bf16x8*>(&phiZ[(size_t)b * 98304 + (size_t)bi * 512 + l * 8]) = r;
}

// ---------------- K5: y = E @ phiZ^T, 32 rows/wave, depth-3 prefetch ----------------
__global__ __launch_bounds__(64, 2) void k5_pv(
    const ushort* __restrict__ E, const ushort* __restrict__ phiZ,
    ushort* __restrict__ y, float* __restrict__ ypz, int b0)
{
    int ng2 = blockIdx.x % 50, bl = blockIdx.x / 50;
    int b = b0 + bl;
    int lane = threadIdx.x;
    int lr = lane & 15, lg = lane >> 4;
    const ushort* Eb = E + (size_t)bl * 1228800 + (size_t)(ng2 * 2) * 24 * 512 + lane * 8;
    const ushort* Pb = phiZ + (size_t)b * 98304 + lane * 8;

    f32x4 acc[2][8] = {};
    bf16x8 Ab[3][2], Bb[3][8];
    #pragma unroll
    for (int p = 0; p < 3; ++p) {
        Ab[p][0] = *reinterpret_cast<const bf16x8*>(&Eb[(size_t)p * 512]);
        Ab[p][1] = *reinterpret_cast<const bf16x8*>(&Eb[(size_t)(24 + p) * 512]);
        #pragma unroll
        for (int cf = 0; cf < 8; ++cf)
            Bb[p][cf] = *reinterpret_cast<const bf16x8*>(&Pb[(size_t)(cf * 24 + p) * 512]);
    }
    #pragma unroll
    for (int kc = 0; kc < 24; ++kc) {
        int cur = kc % 3;
        bf16x8 a0 = Ab[cur][0], a1 = Ab[cur][1];
        #pragma unroll
        for (int cf = 0; cf < 8; ++cf) {
            bf16x8 bbv = Bb[cur][cf];
            acc[0][cf] = __builtin_amdgcn_mfma_f32_16x16x32_bf16(a0, bbv, acc[0][cf], 0, 0, 0);
            acc[1][cf] = __builtin_amdgcn_mfma_f32_16x16x32_bf16(a1, bbv, acc[1][cf], 0, 0, 0);
        }
        if (kc + 3 < 24) {
            Ab[cur][0] = *reinterpret_cast<const bf16x8*>(&Eb[(size_t)(kc + 3) * 512]);
            Ab[cur][1] = *reinterpret_cast<const bf16x8*>(&Eb[(size_t)(24 + kc + 3) * 512]);
            #pragma unroll
            for (int cf = 0; cf < 8; ++cf)
                Bb[cur][cf] = *reinterpret_cast<const bf16x8*>(
                    &Pb[(size_t)(cf * 24 + kc + 3) * 512]);
        }
    }

    #pragma unroll
    for (int m = 0; m < 2; ++m) {
        int ng = ng2 * 2 + m;
        int nrow = ng * 16;
        #pragma unroll
        for (int cf = 0; cf < 8; ++cf) {
            float se = 0.f;
            #pragma unroll
            for (int r = 0; r < 4; ++r) {
                ushort hv = f2bf(acc[m][cf][r]);
                y[((size_t)b * 1600 + nrow + lg * 4 + r) * 128 + cf * 16 + lr] = hv;
                se += __expf(bf2f(hv));
            }
            se += __shfl_xor(se, 16);
            se += __shfl_xor(se, 32);
            if (lane < 16)
                ypz[((size_t)ng * 64 + b) * 128 + cf * 16 + lane] = se;
        }
    }
}

// ---------------- K6b: combine 100 plane-major partials -> 1/Z2 per (b,c) ----------------
__global__ void k6b_ycomb(const float* __restrict__ ypz, float* __restrict__ yzi)
{
    int idx = blockIdx.x * 256 + threadIdx.x;
    if (idx >= 64 * 128) return;
    float z = 0.f;
    for (int ng = 0; ng < 100; ++ng) z += ypz[(size_t)ng * 8192 + idx];
    yzi[idx] = 1.f / z;
}

// ---------------- K7: softmax(y) -> conv W + residual + BN + ReLU ----------------
// round-10 structure; x prefetched into registers at kernel start (latency hiding).
__global__ __launch_bounds__(256) void k7_final(
    const ushort* __restrict__ y, const float* __restrict__ yzi,
    const ushort* __restrict__ Wbf, const float* __restrict__ Wb,
    const float* __restrict__ x,
    const float* __restrict__ gamma, const float* __restrict__ beta,
    const float* __restrict__ mean, const float* __restrict__ var,
    float* __restrict__ out)
{
    int nt = blockIdx.x % NTB, b = blockIdx.x / NTB;
    int n0 = nt * 64;
    __shared__ ushort yl[64][136];
    __shared__ float scl[256], shl[256], wbl[256], zl[128];
    int t = threadIdx.x, lane = t & 63, w = t >> 6;
    int lr = lane & 15, lg = lane >> 4;
    int o0 = w * 64;

    // hoisted x prefetch: 64 independent loads in flight under staging+MFMA
    float xr[4][4][4];
    #pragma unroll
    for (int mi = 0; mi < 4; ++mi)
        #pragma unroll
        for (int ni = 0; ni < 4; ++ni) {
            int n = n0 + ni * 16 + lr;
            #pragma unroll
            for (int r = 0; r < 4; ++r) {
                int o = o0 + mi * 16 + lg * 4 + r;
                xr[mi][ni][r] = x[((size_t)b * 256 + o) * 1600 + n];
            }
        }

    {
        float sc = gamma[t] * rsqrtf(var[t] + 1e-5f);
        scl[t] = sc;
        shl[t] = beta[t] - mean[t] * sc;
        wbl[t] = Wb[t];
        if (t < 128) zl[t] = yzi[(size_t)b * 128 + t];
    }
    __syncthreads();
    int c8 = (t & 15) * 8, rr = t >> 4;
    #pragma unroll
    for (int p = 0; p < 4; ++p) {
        int r = rr + 16 * p;
        bf16x8 v = *reinterpret_cast<const bf16x8*>(
            &y[((size_t)b * 1600 + n0 + r) * 128 + c8]);
        bf16x8 pk;
        #pragma unroll
        for (int j = 0; j < 8; ++j) {
            float f = bf2f((ushort)v[j]);
            pk[j] = (short)f2bf(__expf(f) * zl[c8 + j]);
        }
        *reinterpret_cast<bf16x8*>(&yl[r][c8]) = pk;
    }
    __syncthreads();
    f32x4 acc[4][4] = {};
    #pragma unroll
    for (int kc = 0; kc < 4; ++kc) {
        bf16x8 af[4];
        #pragma unroll
        for (int mi = 0; mi < 4; ++mi)
            af[mi] = *reinterpret_cast<const bf16x8*>(
                &Wbf[(size_t)(((o0 >> 4) + mi) * 4 + kc) * 512 + lane * 8]);
        #pragma unroll
        for (int ni = 0; ni < 4; ++ni) {
            bf16x8 bfrag = *reinterpret_cast<const bf16x8*>(&yl[ni * 16 + lr][kc * 32 + lg * 8]);
            #pragma unroll
            for (int mi = 0; mi < 4; ++mi)
                acc[mi][ni] = __builtin_amdgcn_mfma_f32_16x16x32_bf16(
                    af[mi], bfrag, acc[mi][ni], 0, 0, 0);
        }
    }
    #pragma unroll
    for (int mi = 0; mi < 4; ++mi)
        #pragma unroll
        for (int ni = 0; ni < 4; ++ni) {
            int n = n0 + ni * 16 + lr;
            #pragma unroll
            for (int r = 0; r < 4; ++r) {
                int o = o0 + mi * 16 + lg * 4 + r;
                size_t off = ((size_t)b * 256 + o) * 1600 + n;
                float v = (acc[mi][ni][r] + wbl[o] + xr[mi][ni][r]) * scl[o] + shl[o];
                out[off] = fmaxf(v, 0.f);
            }
        }
}

extern "C" void kernel_launch(void* const* d_in, const int* in_sizes, int n_in,
                              void* d_out, int out_size, void* d_ws, size_t ws_size,
                              hipStream_t stream)
{
    const float* x   = (const float*)d_in[0];
    const float* gw  = (const float*)d_in[1];
    const float* gb  = (const float*)d_in[2];
    const float* tw  = (const float*)d_in[3];
    const float* tb  = (const float*)d_in[4];
    const float* Ww  = (const float*)d_in[5];
    const float* Wb  = (const float*)d_in[6];
    const float* bng = (const float*)d_in[7];
    const float* bnb = (const float*)d_in[8];
    const float* bnm = (const float*)d_in[9];
    const float* bnv = (const float*)d_in[10];
    float* out = (float*)d_out;

    char* base = (char*)d_ws;
    ushort* thT  = (ushort*)(base);               // 26,214,400 B (frag-swz)
    ushort* gout = (ushort*)(base + 26214400);    // 26,214,400 B (reused as y)
    ushort* phiC = (ushort*)(base + 52428800);    // 12,582,912 B (row-major)
    ushort* phiT = (ushort*)(base + 65011712);    // 12,582,912 B (frag-swz)
    float* psum  = (float*)(base + 77594624);     //  4,915,200 B  [nt][b][s]
    ushort* phiZ = (ushort*)(base + 82509824);    // 12,582,912 B (frag-swz)
    float* zinv  = (float*)(base + 95092736);     //    196,608 B
    float* ypz   = (float*)(base + 95289344);     //  3,276,800 B  [ng][b][c]
    float* yzi   = (float*)(base + 98566144);     //     32,768 B
    ushort* Wbf  = (ushort*)(base + 98598912);    //     65,536 B (frag-swz)
    ushort* gwb  = (ushort*)(base + 98664448);    //     65,536 B (frag-swz)
    ushort* twb  = (ushort*)(base + 98729984);    //     65,536 B (frag-swz)
    ushort* yv   = gout;                          // alias: gout dead after k2a
    ushort* xT   = (ushort*)d_out;                // scratch in out region
    ushort* E    = (ushort*)d_out;

    k0_wconv<<<48, 256, 0, stream>>>(gw, tw, Ww, gwb, twb, Wbf);
    k1a_xpose<<<64 * 4 * NTB, 256, 0, stream>>>(x, xT);
    k1b_conv<<<64 * NTB, 256, 0, stream>>>(xT, gwb, gb, twb, tb, gout, thT);
    k2a_psp<<<64 * 8, 256, 0, stream>>>(gout, phiC, phiT);

    // half 0: batches 0..31
    k3_expf<<<32 * 25 * 12, 256, 0, stream>>>(thT, phiT, E, psum, 0);
    k4a_zinv<<<96, 256, 0, stream>>>(psum, zinv, 0);
    k4b_scale<<<1536, 256, 0, stream>>>(phiC, zinv, phiZ);
    k5_pv<<<32 * 50, 64, 0, stream>>>(E, phiZ, yv, ypz, 0);

    // half 1: batches 32..63
    k3_expf<<<32 * 25 * 12, 256, 0, stream>>>(thT, phiT, E, psum, 32);
    k4a_zinv<<<96, 256, 0, stream>>>(psum, zinv, 32);
    k4b_scale<<<1536, 256, 0, stream>>>(phiC + (size_t)32 * 128 * 768, zinv,
                                        phiZ + (size_t)32 * 98304);
    k5_pv<<<32 * 50, 64, 0, stream>>>(E, phiZ, yv, ypz, 32);

    k6b_ycomb<<<32, 256, 0, stream>>>(ypz, yzi);
    k7_final<<<64 * NTB, 256, 0, stream>>>(yv, yzi, Wbf, Wb, x, bng, bnb, bnm, bnv, out);
}